// Round 19
// baseline (256.502 us; speedup 1.0000x reference)
//
#include <hip/hip_runtime.h>
#include <hip/hip_bf16.h>
#include <math.h>

#define T 1024
#define SEQ 512
#define BATCH 2
#define D 768
#define H 12
#define DH 64
#define DL 64
#define E 8
#define HID 3072

typedef __attribute__((ext_vector_type(8))) short bf16x8;
typedef __attribute__((ext_vector_type(4))) float f32x4;

__device__ inline short f2bf(float f) {
    __hip_bfloat16 h = __float2bfloat16(f);
    return *reinterpret_cast<short*>(&h);
}

// LDS-only barrier: publishes ds ops without draining in-flight global loads.
// (__syncthreads would emit s_waitcnt vmcnt(0) and kill cross-iter prefetch.)
__device__ inline void lds_barrier() {
    __builtin_amdgcn_sched_barrier(0);
    asm volatile("s_waitcnt lgkmcnt(0)" ::: "memory");
    __builtin_amdgcn_s_barrier();
    __builtin_amdgcn_sched_barrier(0);
}

// attn swizzle (validated)
__device__ inline int swz(int row, int k) { return (row * 64 + k) ^ ((row & 7) << 3); }
// GEMM swizzle (validated R9/R10)
__device__ inline int swzB(int row, int k) { return row * 64 + (k ^ (((row >> 1) & 7) << 3)); }

// ---------------- rmsnorm (dual fp32 + bf16 output) ----------------
__global__ void rmsnorm_kernel(const float* __restrict__ x, const float* __restrict__ w,
                               float* __restrict__ out, short* __restrict__ outb) {
    int t = blockIdx.x;
    int tid = threadIdx.x; // 256
    const float* xr = x + (size_t)t * D;
    float s = 0.f;
    for (int i = tid; i < D; i += 256) { float v = xr[i]; s += v * v; }
    __shared__ float red[256];
    red[tid] = s; __syncthreads();
    for (int o = 128; o > 0; o >>= 1) { if (tid < o) red[tid] += red[tid + o]; __syncthreads(); }
    float scale = 1.0f / sqrtf(red[0] / (float)D + 1e-6f);
    for (int i = tid; i < D; i += 256) {
        float v = xr[i] * scale * w[i];
        out[(size_t)t * D + i] = v;
        outb[(size_t)t * D + i] = f2bf(v);
    }
}

// ---------------- dense bf16 MFMA GEMM (unchanged, validated) ----------------
template<bool RES>
__global__ __launch_bounds__(256) void gemm_bf16(
    const float* __restrict__ A, const float* __restrict__ B,
    const float* __restrict__ Rp, float* __restrict__ C,
    int M, int N, int K) {
    int mb = blockIdx.y * 64, nb = blockIdx.x * 64;
    __shared__ short As[64 * 64];
    __shared__ short Bs[64 * 64];
    int tid = threadIdx.x;
    int lane = tid & 63, wave = tid >> 6;
    int wr = wave >> 1, wc = wave & 1;
    f32x4 acc[2][2] = {};
    int ar = tid >> 2, ac = (tid & 3) * 16;
    int bn = (tid & 15) * 4, bk = (tid >> 4) * 4;
    const float* Arow = A + (size_t)(mb + ar) * K + ac;
    const float* Bg = B + nb;
    float4 a_c[4], b_c[4];
#pragma unroll
    for (int j = 0; j < 4; j++) a_c[j] = *(const float4*)(Arow + j * 4);
#pragma unroll
    for (int i = 0; i < 4; i++) b_c[i] = *(const float4*)(Bg + (size_t)(bk + i) * N + bn);
    for (int k0 = 0; k0 < K; k0 += 64) {
        float4 a_n[4], b_n[4];
        bool more = (k0 + 64) < K;
        if (more) {
#pragma unroll
            for (int j = 0; j < 4; j++) a_n[j] = *(const float4*)(Arow + k0 + 64 + j * 4);
#pragma unroll
            for (int i = 0; i < 4; i++) b_n[i] = *(const float4*)(Bg + (size_t)(k0 + 64 + bk + i) * N + bn);
        }
#pragma unroll
        for (int j = 0; j < 4; j++)
            *(short4*)&As[swzB(ar, ac + j * 4)] =
                make_short4(f2bf(a_c[j].x), f2bf(a_c[j].y), f2bf(a_c[j].z), f2bf(a_c[j].w));
        *(short4*)&Bs[swzB(bn + 0, bk)] = make_short4(f2bf(b_c[0].x), f2bf(b_c[1].x), f2bf(b_c[2].x), f2bf(b_c[3].x));
        *(short4*)&Bs[swzB(bn + 1, bk)] = make_short4(f2bf(b_c[0].y), f2bf(b_c[1].y), f2bf(b_c[2].y), f2bf(b_c[3].y));
        *(short4*)&Bs[swzB(bn + 2, bk)] = make_short4(f2bf(b_c[0].z), f2bf(b_c[1].z), f2bf(b_c[2].z), f2bf(b_c[3].z));
        *(short4*)&Bs[swzB(bn + 3, bk)] = make_short4(f2bf(b_c[0].w), f2bf(b_c[1].w), f2bf(b_c[2].w), f2bf(b_c[3].w));
        __syncthreads();
#pragma unroll
        for (int kk = 0; kk < 64; kk += 32) {
            int krd = kk + 8 * (lane >> 4);
            bf16x8 a0 = *(const bf16x8*)&As[swzB(wr * 32 + (lane & 15), krd)];
            bf16x8 a1 = *(const bf16x8*)&As[swzB(wr * 32 + 16 + (lane & 15), krd)];
            bf16x8 b0 = *(const bf16x8*)&Bs[swzB(wc * 32 + (lane & 15), krd)];
            bf16x8 b1 = *(const bf16x8*)&Bs[swzB(wc * 32 + 16 + (lane & 15), krd)];
            acc[0][0] = __builtin_amdgcn_mfma_f32_16x16x32_bf16(a0, b0, acc[0][0], 0, 0, 0);
            acc[0][1] = __builtin_amdgcn_mfma_f32_16x16x32_bf16(a0, b1, acc[0][1], 0, 0, 0);
            acc[1][0] = __builtin_amdgcn_mfma_f32_16x16x32_bf16(a1, b0, acc[1][0], 0, 0, 0);
            acc[1][1] = __builtin_amdgcn_mfma_f32_16x16x32_bf16(a1, b1, acc[1][1], 0, 0, 0);
        }
        __syncthreads();
        if (more) {
#pragma unroll
            for (int j = 0; j < 4; j++) { a_c[j] = a_n[j]; b_c[j] = b_n[j]; }
        }
    }
#pragma unroll
    for (int mi = 0; mi < 2; mi++)
#pragma unroll
        for (int ni = 0; ni < 2; ni++)
#pragma unroll
            for (int r = 0; r < 4; r++) {
                int row = mb + wr * 32 + mi * 16 + (lane >> 4) * 4 + r;
                int col = nb + wc * 32 + ni * 16 + (lane & 15);
                float val = acc[mi][ni][r];
                if (RES) val += Rp[(size_t)row * N + col];
                C[(size_t)row * N + col] = val;
            }
}

// ---- fused K/V up-projection (unchanged, validated) ----
__global__ __launch_bounds__(256) void gemm_kuv(
    const float* __restrict__ A, const float* __restrict__ Bk, const float* __restrict__ Bv,
    float* __restrict__ Ck, float* __restrict__ Cv, int M, int N, int K) {
    int mb = blockIdx.y * 64, nb = blockIdx.x * 64;
    __shared__ short As[64 * 64];
    __shared__ short B1s[64 * 64];
    __shared__ short B2s[64 * 64];
    int tid = threadIdx.x;
    int lane = tid & 63, wave = tid >> 6;
    int wr = wave >> 1, wc = wave & 1;
    f32x4 acc1[2][2] = {};
    f32x4 acc2[2][2] = {};
    int ar = tid >> 2, ac = (tid & 3) * 16;
    int bn = (tid & 15) * 4, bk = (tid >> 4) * 4;
    const float* Arow = A + (size_t)(mb + ar) * K + ac;
    {
        float4 a_c[4], p_c[4], q_c[4];
#pragma unroll
        for (int j = 0; j < 4; j++) a_c[j] = *(const float4*)(Arow + j * 4);
#pragma unroll
        for (int i = 0; i < 4; i++) {
            p_c[i] = *(const float4*)(Bk + (size_t)(bk + i) * N + nb + bn);
            q_c[i] = *(const float4*)(Bv + (size_t)(bk + i) * N + nb + bn);
        }
#pragma unroll
        for (int j = 0; j < 4; j++)
            *(short4*)&As[swzB(ar, ac + j * 4)] =
                make_short4(f2bf(a_c[j].x), f2bf(a_c[j].y), f2bf(a_c[j].z), f2bf(a_c[j].w));
        *(short4*)&B1s[swzB(bn + 0, bk)] = make_short4(f2bf(p_c[0].x), f2bf(p_c[1].x), f2bf(p_c[2].x), f2bf(p_c[3].x));
        *(short4*)&B1s[swzB(bn + 1, bk)] = make_short4(f2bf(p_c[0].y), f2bf(p_c[1].y), f2bf(p_c[2].y), f2bf(p_c[3].y));
        *(short4*)&B1s[swzB(bn + 2, bk)] = make_short4(f2bf(p_c[0].z), f2bf(p_c[1].z), f2bf(p_c[2].z), f2bf(p_c[3].z));
        *(short4*)&B1s[swzB(bn + 3, bk)] = make_short4(f2bf(p_c[0].w), f2bf(p_c[1].w), f2bf(p_c[2].w), f2bf(p_c[3].w));
        *(short4*)&B2s[swzB(bn + 0, bk)] = make_short4(f2bf(q_c[0].x), f2bf(q_c[1].x), f2bf(q_c[2].x), f2bf(q_c[3].x));
        *(short4*)&B2s[swzB(bn + 1, bk)] = make_short4(f2bf(q_c[0].y), f2bf(q_c[1].y), f2bf(q_c[2].y), f2bf(q_c[3].y));
        *(short4*)&B2s[swzB(bn + 2, bk)] = make_short4(f2bf(q_c[0].z), f2bf(q_c[1].z), f2bf(q_c[2].z), f2bf(q_c[3].z));
        *(short4*)&B2s[swzB(bn + 3, bk)] = make_short4(f2bf(q_c[0].w), f2bf(q_c[1].w), f2bf(q_c[2].w), f2bf(q_c[3].w));
    }
    __syncthreads();
#pragma unroll
    for (int kk = 0; kk < 64; kk += 32) {
        int krd = kk + 8 * (lane >> 4);
        bf16x8 a0 = *(const bf16x8*)&As[swzB(wr * 32 + (lane & 15), krd)];
        bf16x8 a1 = *(const bf16x8*)&As[swzB(wr * 32 + 16 + (lane & 15), krd)];
        bf16x8 p0 = *(const bf16x8*)&B1s[swzB(wc * 32 + (lane & 15), krd)];
        bf16x8 p1 = *(const bf16x8*)&B1s[swzB(wc * 32 + 16 + (lane & 15), krd)];
        bf16x8 q0 = *(const bf16x8*)&B2s[swzB(wc * 32 + (lane & 15), krd)];
        bf16x8 q1 = *(const bf16x8*)&B2s[swzB(wc * 32 + 16 + (lane & 15), krd)];
        acc1[0][0] = __builtin_amdgcn_mfma_f32_16x16x32_bf16(a0, p0, acc1[0][0], 0, 0, 0);
        acc1[0][1] = __builtin_amdgcn_mfma_f32_16x16x32_bf16(a0, p1, acc1[0][1], 0, 0, 0);
        acc1[1][0] = __builtin_amdgcn_mfma_f32_16x16x32_bf16(a1, p0, acc1[1][0], 0, 0, 0);
        acc1[1][1] = __builtin_amdgcn_mfma_f32_16x16x32_bf16(a1, p1, acc1[1][1], 0, 0, 0);
        acc2[0][0] = __builtin_amdgcn_mfma_f32_16x16x32_bf16(a0, q0, acc2[0][0], 0, 0, 0);
        acc2[0][1] = __builtin_amdgcn_mfma_f32_16x16x32_bf16(a0, q1, acc2[0][1], 0, 0, 0);
        acc2[1][0] = __builtin_amdgcn_mfma_f32_16x16x32_bf16(a1, q0, acc2[1][0], 0, 0, 0);
        acc2[1][1] = __builtin_amdgcn_mfma_f32_16x16x32_bf16(a1, q1, acc2[1][1], 0, 0, 0);
    }
#pragma unroll
    for (int mi = 0; mi < 2; mi++)
#pragma unroll
        for (int ni = 0; ni < 2; ni++)
#pragma unroll
            for (int r = 0; r < 4; r++) {
                int row = mb + wr * 32 + mi * 16 + (lane >> 4) * 4 + r;
                int col = nb + wc * 32 + ni * 16 + (lane & 15);
                Ck[(size_t)row * N + col] = acc1[mi][ni][r];
                Cv[(size_t)row * N + col] = acc2[mi][ni][r];
            }
}

// ---------------- RoPE (unchanged) ----------------
__global__ void rope_kernel(float* __restrict__ qb, float* __restrict__ kb,
                            const int* __restrict__ spp) {
    int p = blockIdx.x * 256 + threadIdx.x; // T*H*32
    if (p >= T * H * 32) return;
    int i = p & 31;
    int rem = p >> 5;
    int h = rem % H;
    int ts = rem / H;
    int s = ts % SEQ;
    float invf = powf(10000.0f, -(float)(2 * i) / 64.0f);
    float ang = (float)(s + spp[0]) * invf;
    float c = cosf(ang), sn = sinf(ang);
    size_t base = (size_t)ts * D + h * DH;
    float x1 = qb[base + i], x2 = qb[base + 32 + i];
    qb[base + i] = x1 * c - x2 * sn;
    qb[base + 32 + i] = x1 * sn + x2 * c;
    x1 = kb[base + i]; x2 = kb[base + 32 + i];
    kb[base + i] = x1 * c - x2 * sn;
    kb[base + 32 + i] = x1 * sn + x2 * c;
}

// ---------------- flash attention (unchanged) ----------------
__global__ __launch_bounds__(256) void attn_mfma(
    const float* __restrict__ q, const float* __restrict__ k,
    const float* __restrict__ v, float* __restrict__ a) {
    int qt = blockIdx.x, h = blockIdx.y, b = blockIdx.z;
    int tid = threadIdx.x, lane = tid & 63, wave = tid >> 6;
    __shared__ short Qs[64 * 64];
    __shared__ short Ks[64 * 64];
    __shared__ short Vs[64 * 64];
    __shared__ short Ps[64 * 64];
    int qbase = qt * 64;
    {
        int r = tid >> 2, d0 = (tid & 3) * 16;
        const float* src = q + ((size_t)(b * SEQ + qbase + r)) * D + h * DH + d0;
#pragma unroll
        for (int j = 0; j < 4; j++) {
            float4 vv = *(const float4*)(src + j * 4);
            *(short4*)&Qs[swz(r, d0 + j * 4)] =
                make_short4(f2bf(vv.x), f2bf(vv.y), f2bf(vv.z), f2bf(vv.w));
        }
    }
    __syncthreads();
    bf16x8 qf0 = *(const bf16x8*)&Qs[swz(wave * 16 + (lane & 15), 8 * (lane >> 4))];
    bf16x8 qf1 = *(const bf16x8*)&Qs[swz(wave * 16 + (lane & 15), 32 + 8 * (lane >> 4))];

    float m_run[4] = {-1e30f, -1e30f, -1e30f, -1e30f};
    float l_run[4] = {0.f, 0.f, 0.f, 0.f};
    f32x4 o[4] = {};

    for (int kt = 0; kt <= qt; kt++) {
        int kvbase = kt * 64;
        {
            int r = tid >> 2, d0 = (tid & 3) * 16;
            const float* src = k + ((size_t)(b * SEQ + kvbase + r)) * D + h * DH + d0;
#pragma unroll
            for (int j = 0; j < 4; j++) {
                float4 vv = *(const float4*)(src + j * 4);
                *(short4*)&Ks[swz(r, d0 + j * 4)] =
                    make_short4(f2bf(vv.x), f2bf(vv.y), f2bf(vv.z), f2bf(vv.w));
            }
        }
#pragma unroll
        for (int i = 0; i < 4; i++) {
            int idx = tid + i * 256;
            int kr = idx >> 4, d0 = (idx & 15) * 4;
            float4 vv = *(const float4*)(v + ((size_t)(b * SEQ + kvbase + kr)) * D + h * DH + d0);
            Vs[swz(d0 + 0, kr)] = f2bf(vv.x); Vs[swz(d0 + 1, kr)] = f2bf(vv.y);
            Vs[swz(d0 + 2, kr)] = f2bf(vv.z); Vs[swz(d0 + 3, kr)] = f2bf(vv.w);
        }
        __syncthreads();

        f32x4 s[4];
#pragma unroll
        for (int kvt = 0; kvt < 4; kvt++) {
            bf16x8 kf0 = *(const bf16x8*)&Ks[swz(kvt * 16 + (lane & 15), 8 * (lane >> 4))];
            bf16x8 kf1 = *(const bf16x8*)&Ks[swz(kvt * 16 + (lane & 15), 32 + 8 * (lane >> 4))];
            f32x4 z = {};
            z = __builtin_amdgcn_mfma_f32_16x16x32_bf16(qf0, kf0, z, 0, 0, 0);
            z = __builtin_amdgcn_mfma_f32_16x16x32_bf16(qf1, kf1, z, 0, 0, 0);
            s[kvt] = z;
        }
#pragma unroll
        for (int kvt = 0; kvt < 4; kvt++) {
#pragma unroll
            for (int r = 0; r < 4; r++) {
                float val = s[kvt][r] * 0.125f;
                if (kt == qt) {
                    int kv_abs = kvbase + kvt * 16 + (lane & 15);
                    int q_abs = qbase + wave * 16 + (lane >> 4) * 4 + r;
                    if (kv_abs > q_abs) val = -1e30f;
                }
                s[kvt][r] = val;
            }
        }
        float mnew[4], psum[4], scl[4];
#pragma unroll
        for (int r = 0; r < 4; r++) {
            float mx = fmaxf(fmaxf(s[0][r], s[1][r]), fmaxf(s[2][r], s[3][r]));
#pragma unroll
            for (int o2 = 8; o2 > 0; o2 >>= 1) mx = fmaxf(mx, __shfl_xor(mx, o2));
            mnew[r] = fmaxf(m_run[r], mx);
            float ps = 0.f;
#pragma unroll
            for (int kvt = 0; kvt < 4; kvt++) {
                float p = expf(s[kvt][r] - mnew[r]);
                s[kvt][r] = p;
                ps += p;
            }
#pragma unroll
            for (int o2 = 8; o2 > 0; o2 >>= 1) ps += __shfl_xor(ps, o2);
            psum[r] = ps;
            scl[r] = expf(m_run[r] - mnew[r]);
            m_run[r] = mnew[r];
            l_run[r] = l_run[r] * scl[r] + psum[r];
        }
#pragma unroll
        for (int dt = 0; dt < 4; dt++)
#pragma unroll
            for (int r = 0; r < 4; r++) o[dt][r] *= scl[r];
#pragma unroll
        for (int kvt = 0; kvt < 4; kvt++)
#pragma unroll
            for (int r = 0; r < 4; r++)
                Ps[swz(wave * 16 + (lane >> 4) * 4 + r, kvt * 16 + (lane & 15))] = f2bf(s[kvt][r]);
        __syncthreads();
        bf16x8 pa0 = *(const bf16x8*)&Ps[swz(wave * 16 + (lane & 15), 8 * (lane >> 4))];
        bf16x8 pa1 = *(const bf16x8*)&Ps[swz(wave * 16 + (lane & 15), 32 + 8 * (lane >> 4))];
#pragma unroll
        for (int dt = 0; dt < 4; dt++) {
            bf16x8 vf0 = *(const bf16x8*)&Vs[swz(dt * 16 + (lane & 15), 8 * (lane >> 4))];
            bf16x8 vf1 = *(const bf16x8*)&Vs[swz(dt * 16 + (lane & 15), 32 + 8 * (lane >> 4))];
            o[dt] = __builtin_amdgcn_mfma_f32_16x16x32_bf16(pa0, vf0, o[dt], 0, 0, 0);
            o[dt] = __builtin_amdgcn_mfma_f32_16x16x32_bf16(pa1, vf1, o[dt], 0, 0, 0);
        }
        __syncthreads();
    }
#pragma unroll
    for (int r = 0; r < 4; r++) {
        float inv = 1.0f / l_run[r];
        int qrow = qbase + wave * 16 + (lane >> 4) * 4 + r;
#pragma unroll
        for (int dt = 0; dt < 4; dt++) {
            a[((size_t)(b * SEQ + qrow)) * D + h * DH + dt * 16 + (lane & 15)] = o[dt][r] * inv;
        }
    }
}

// ---------------- routing (unchanged) ----------------
__global__ void routing_kernel(const float* __restrict__ h2, const float* __restrict__ gw,
                               float* __restrict__ probs, int* __restrict__ list,
                               int* __restrict__ counts, float* __restrict__ wtok) {
    int t = blockIdx.x;
    int tid = threadIdx.x; // 64
    __shared__ float part[64][8];
    float l[8] = {0.f, 0.f, 0.f, 0.f, 0.f, 0.f, 0.f, 0.f};
    const float* hr = h2 + (size_t)t * D;
    for (int i = tid; i < D; i += 64) {
        float hv = hr[i];
        const float* g = gw + (size_t)i * E;
#pragma unroll
        for (int e = 0; e < 8; e++) l[e] += hv * g[e];
    }
#pragma unroll
    for (int e = 0; e < 8; e++) part[tid][e] = l[e];
    __syncthreads();
    if (tid == 0) {
        float lg[8];
#pragma unroll
        for (int e = 0; e < 8; e++) {
            float s = 0.f;
            for (int j = 0; j < 64; j++) s += part[j][e];
            lg[e] = s;
        }
        float m = lg[0];
#pragma unroll
        for (int e = 1; e < 8; e++) m = fmaxf(m, lg[e]);
        float se = 0.f;
        float pr[8];
#pragma unroll
        for (int e = 0; e < 8; e++) { pr[e] = expf(lg[e] - m); se += pr[e]; }
#pragma unroll
        for (int e = 0; e < 8; e++) { pr[e] /= se; probs[t * 8 + e] = pr[e]; }
        int i0 = 0;
#pragma unroll
        for (int e = 1; e < 8; e++) if (pr[e] > pr[i0]) i0 = e;
        int i1 = -1;
#pragma unroll
        for (int e = 0; e < 8; e++) {
            if (e == i0) continue;
            if (i1 < 0 || pr[e] > pr[i1]) i1 = e;
        }
        float w0 = pr[i0], w1 = pr[i1];
        float wsum = w0 + w1;
        wtok[t * 2 + 0] = w0 / wsum;
        wtok[t * 2 + 1] = w1 / wsum;
        int p0 = atomicAdd(&counts[i0], 1); list[i0 * T + p0] = t * 2 + 0;
        int p1 = atomicAdd(&counts[i1], 1); list[i1 * T + p1] = t * 2 + 1;
    }
}

// ---- MoE tile-map setup (unchanged) ----
__global__ void moe_setup_kernel(const int* __restrict__ counts,
                                 int* __restrict__ m2e_u, int* __restrict__ m2mb_u,
                                 int* __restrict__ m2e_d, int* __restrict__ m2mb_d,
                                 int* __restrict__ ntm) {
    if (threadIdx.x == 0 && blockIdx.x == 0) {
        int idx = 0;
        for (int e = 0; e < E; e++) {
            int nt = (counts[e] + 127) >> 7;
            for (int i = 0; i < nt; i++) { m2e_u[idx] = e; m2mb_u[idx] = i * 128; idx++; }
        }
        ntm[0] = idx;
        idx = 0;
        for (int e = 0; e < E; e++) {
            int nt = (counts[e] + 63) >> 6;
            for (int i = 0; i < nt; i++) { m2e_d[idx] = e; m2mb_d[idx] = i * 64; idx++; }
        }
        ntm[1] = idx;
    }
}

// ---------------- aux loss (unchanged) ----------------
__global__ void aux_kernel(const float* __restrict__ probs, const int* __restrict__ counts,
                           float* __restrict__ out_aux) {
    int tid = threadIdx.x;
    __shared__ float ps[8];
    if (tid < 8) {
        float s = 0.f;
        for (int t = 0; t < T; t++) s += probs[t * 8 + tid];
        ps[tid] = s;
    }
    __syncthreads();
    if (tid == 0) {
        float aux = 0.f;
        for (int e = 0; e < 8; e++) {
            float f = (float)counts[e] / (float)T;
            float P = ps[e] / (float)T;
            aux += f * P;
        }
        out_aux[0] = (float)E * aux;
    }
}

// ---- MoE up: BM=128 x BN=64, bf16 A, LDS dbuf + lds_barrier (loads stay in flight) ----
__global__ __launch_bounds__(256) void moe_up_mfma(
    const short* __restrict__ h2b, const float* __restrict__ w1, const float* __restrict__ w3,
    const int* __restrict__ list, const int* __restrict__ counts,
    const int* __restrict__ m2e, const int* __restrict__ m2mb, const int* __restrict__ ntm,
    short* __restrict__ g) {
    int mi = blockIdx.y;
    if (mi >= ntm[0]) return;
    int e = m2e[mi];
    int mb = m2mb[mi];
    int n = counts[e];
    int nb = blockIdx.x * 64;
    const float* B1g = w1 + (size_t)e * D * HID + nb;
    const float* B3g = w3 + (size_t)e * D * HID + nb;
    __shared__ short As[2][128 * 64];
    __shared__ short B1s[2][64 * 64];
    __shared__ short B3s[2][64 * 64];
    __shared__ int rowpid[128];
    __shared__ int rowtok[128];
    int tid = threadIdx.x;
    int lane = tid & 63, wave = tid >> 6;
    int wr = wave >> 1, wc = wave & 1;
    if (tid < 128) {
        int r = mb + tid;
        int pid = (r < n) ? list[e * T + r] : list[e * T];
        rowpid[tid] = pid;
        rowtok[tid] = pid >> 1;
    }
    __syncthreads();

    f32x4 acc1[4][2] = {};
    f32x4 acc3[4][2] = {};
    int ar = tid >> 1, ac = (tid & 1) * 32;
    int bn = (tid & 15) * 4, bk = (tid >> 4) * 4;
    const short* Arow = h2b + (size_t)rowtok[ar] * D + ac;

    bf16x8 a_r[4];
    float4 b1_r[4], b3_r[4];
    // prologue: tile0 -> regs -> buf0
#pragma unroll
    for (int j = 0; j < 4; j++) a_r[j] = *(const bf16x8*)(Arow + j * 8);
#pragma unroll
    for (int i = 0; i < 4; i++) {
        b1_r[i] = *(const float4*)(B1g + (size_t)(bk + i) * HID + bn);
        b3_r[i] = *(const float4*)(B3g + (size_t)(bk + i) * HID + bn);
    }
#pragma unroll
    for (int j = 0; j < 4; j++) *(bf16x8*)&As[0][swzB(ar, ac + j * 8)] = a_r[j];
    *(short4*)&B1s[0][swzB(bn + 0, bk)] = make_short4(f2bf(b1_r[0].x), f2bf(b1_r[1].x), f2bf(b1_r[2].x), f2bf(b1_r[3].x));
    *(short4*)&B1s[0][swzB(bn + 1, bk)] = make_short4(f2bf(b1_r[0].y), f2bf(b1_r[1].y), f2bf(b1_r[2].y), f2bf(b1_r[3].y));
    *(short4*)&B1s[0][swzB(bn + 2, bk)] = make_short4(f2bf(b1_r[0].z), f2bf(b1_r[1].z), f2bf(b1_r[2].z), f2bf(b1_r[3].z));
    *(short4*)&B1s[0][swzB(bn + 3, bk)] = make_short4(f2bf(b1_r[0].w), f2bf(b1_r[1].w), f2bf(b1_r[2].w), f2bf(b1_r[3].w));
    *(short4*)&B3s[0][swzB(bn + 0, bk)] = make_short4(f2bf(b3_r[0].x), f2bf(b3_r[1].x), f2bf(b3_r[2].x), f2bf(b3_r[3].x));
    *(short4*)&B3s[0][swzB(bn + 1, bk)] = make_short4(f2bf(b3_r[0].y), f2bf(b3_r[1].y), f2bf(b3_r[2].y), f2bf(b3_r[3].y));
    *(short4*)&B3s[0][swzB(bn + 2, bk)] = make_short4(f2bf(b3_r[0].z), f2bf(b3_r[1].z), f2bf(b3_r[2].z), f2bf(b3_r[3].z));
    *(short4*)&B3s[0][swzB(bn + 3, bk)] = make_short4(f2bf(b3_r[0].w), f2bf(b3_r[1].w), f2bf(b3_r[2].w), f2bf(b3_r[3].w));
    lds_barrier();
    // issue loads for tile1
#pragma unroll
    for (int j = 0; j < 4; j++) a_r[j] = *(const bf16x8*)(Arow + 64 + j * 8);
#pragma unroll
    for (int i = 0; i < 4; i++) {
        b1_r[i] = *(const float4*)(B1g + (size_t)(64 + bk + i) * HID + bn);
        b3_r[i] = *(const float4*)(B3g + (size_t)(64 + bk + i) * HID + bn);
    }

    int cur = 0;
    for (int k0 = 0; k0 < D; k0 += 64) {
        bool more = (k0 + 64) < D;
        // write tile k+1 regs to the other buffer (overlaps MFMA on cur)
        if (more) {
            int nx = cur ^ 1;
#pragma unroll
            for (int j = 0; j < 4; j++) *(bf16x8*)&As[nx][swzB(ar, ac + j * 8)] = a_r[j];
            *(short4*)&B1s[nx][swzB(bn + 0, bk)] = make_short4(f2bf(b1_r[0].x), f2bf(b1_r[1].x), f2bf(b1_r[2].x), f2bf(b1_r[3].x));
            *(short4*)&B1s[nx][swzB(bn + 1, bk)] = make_short4(f2bf(b1_r[0].y), f2bf(b1_r[1].y), f2bf(b1_r[2].y), f2bf(b1_r[3].y));
            *(short4*)&B1s[nx][swzB(bn + 2, bk)] = make_short4(f2bf(b1_r[0].z), f2bf(b1_r[1].z), f2bf(b1_r[2].z), f2bf(b1_r[3].z));
            *(short4*)&B1s[nx][swzB(bn + 3, bk)] = make_short4(f2bf(b1_r[0].w), f2bf(b1_r[1].w), f2bf(b1_r[2].w), f2bf(b1_r[3].w));
            *(short4*)&B3s[nx][swzB(bn + 0, bk)] = make_short4(f2bf(b3_r[0].x), f2bf(b3_r[1].x), f2bf(b3_r[2].x), f2bf(b3_r[3].x));
            *(short4*)&B3s[nx][swzB(bn + 1, bk)] = make_short4(f2bf(b3_r[0].y), f2bf(b3_r[1].y), f2bf(b3_r[2].y), f2bf(b3_r[3].y));
            *(short4*)&B3s[nx][swzB(bn + 2, bk)] = make_short4(f2bf(b3_r[0].z), f2bf(b3_r[1].z), f2bf(b3_r[2].z), f2bf(b3_r[3].z));
            *(short4*)&B3s[nx][swzB(bn + 3, bk)] = make_short4(f2bf(b3_r[0].w), f2bf(b3_r[1].w), f2bf(b3_r[2].w), f2bf(b3_r[3].w));
        }
        // issue loads for tile k+2
        if (k0 + 128 < D) {
#pragma unroll
            for (int j = 0; j < 4; j++) a_r[j] = *(const bf16x8*)(Arow + k0 + 128 + j * 8);
#pragma unroll
            for (int i = 0; i < 4; i++) {
                b1_r[i] = *(const float4*)(B1g + (size_t)(k0 + 128 + bk + i) * HID + bn);
                b3_r[i] = *(const float4*)(B3g + (size_t)(k0 + 128 + bk + i) * HID + bn);
            }
        }
        // MFMA on current buffer
#pragma unroll
        for (int kk = 0; kk < 64; kk += 32) {
            int krd = kk + 8 * (lane >> 4);
            bf16x8 b1f[2], b3f[2];
#pragma unroll
            for (int ni = 0; ni < 2; ni++) {
                b1f[ni] = *(const bf16x8*)&B1s[cur][swzB(wc * 32 + ni * 16 + (lane & 15), krd)];
                b3f[ni] = *(const bf16x8*)&B3s[cur][swzB(wc * 32 + ni * 16 + (lane & 15), krd)];
            }
#pragma unroll
            for (int mi2 = 0; mi2 < 4; mi2++) {
                bf16x8 af = *(const bf16x8*)&As[cur][swzB(wr * 64 + mi2 * 16 + (lane & 15), krd)];
                acc1[mi2][0] = __builtin_amdgcn_mfma_f32_16x16x32_bf16(af, b1f[0], acc1[mi2][0], 0, 0, 0);
                acc1[mi2][1] = __builtin_amdgcn_mfma_f32_16x16x32_bf16(af, b1f[1], acc1[mi2][1], 0, 0, 0);
                acc3[mi2][0] = __builtin_amdgcn_mfma_f32_16x16x32_bf16(af, b3f[0], acc3[mi2][0], 0, 0, 0);
                acc3[mi2][1] = __builtin_amdgcn_mfma_f32_16x16x32_bf16(af, b3f[1], acc3[mi2][1], 0, 0, 0);
            }
        }
        lds_barrier();
        cur ^= 1;
    }
#pragma unroll
    for (int mi2 = 0; mi2 < 4; mi2++)
#pragma unroll
        for (int ni = 0; ni < 2; ni++)
#pragma unroll
            for (int r = 0; r < 4; r++) {
                int row = wr * 64 + mi2 * 16 + (lane >> 4) * 4 + r;
                if (mb + row < n) {
                    int pid = rowpid[row];
                    int col = nb + wc * 32 + ni * 16 + (lane & 15);
                    float v1 = acc1[mi2][ni][r], v3 = acc3[mi2][ni][r];
                    float sil = v1 / (1.f + expf(-v1));
                    g[(size_t)pid * HID + col] = f2bf(sil * v3);
                }
            }
}

// ---- MoE down: BM=64, load-after-barrier + lds_barrier ----
__global__ __launch_bounds__(256) void moe_down_mfma(
    const short* __restrict__ g, const float* __restrict__ w2,
    const int* __restrict__ list, const int* __restrict__ counts,
    const int* __restrict__ m2e, const int* __restrict__ m2mb, const int* __restrict__ ntm,
    float* __restrict__ yp) {
    int mi = blockIdx.y;
    if (mi >= ntm[1]) return;
    int e = m2e[mi];
    int mb = m2mb[mi];
    int n = counts[e];
    int nb = blockIdx.x * 64;
    const float* Bg = w2 + (size_t)e * HID * D + nb;
    __shared__ short As[64 * 64];
    __shared__ short Bs[64 * 64];
    __shared__ int rowpid[64];
    int tid = threadIdx.x;
    int lane = tid & 63, wave = tid >> 6;
    int wr = wave >> 1, wc = wave & 1;
    if (tid < 64) {
        int r = mb + tid;
        rowpid[tid] = (r < n) ? list[e * T + r] : list[e * T];
    }
    __syncthreads();

    f32x4 acc[2][2] = {};
    int ar0 = tid >> 3, ak0 = (tid & 7) * 8;
    int ar1 = (tid + 256) >> 3, ak1 = ((tid + 256) & 7) * 8;
    int bn = (tid & 15) * 4, bk = (tid >> 4) * 4;
    const short* Asrc0 = g + (size_t)rowpid[ar0] * HID + ak0;
    const short* Asrc1 = g + (size_t)rowpid[ar1] * HID + ak1;

    bf16x8 a_r0 = *(const bf16x8*)(Asrc0);
    bf16x8 a_r1 = *(const bf16x8*)(Asrc1);
    float4 b_r[4];
#pragma unroll
    for (int i = 0; i < 4; i++) b_r[i] = *(const float4*)(Bg + (size_t)(bk + i) * D + bn);

    for (int k0 = 0; k0 < HID; k0 += 64) {
        *(bf16x8*)&As[swzB(ar0, ak0)] = a_r0;
        *(bf16x8*)&As[swzB(ar1, ak1)] = a_r1;
        *(short4*)&Bs[swzB(bn + 0, bk)] = make_short4(f2bf(b_r[0].x), f2bf(b_r[1].x), f2bf(b_r[2].x), f2bf(b_r[3].x));
        *(short4*)&Bs[swzB(bn + 1, bk)] = make_short4(f2bf(b_r[0].y), f2bf(b_r[1].y), f2bf(b_r[2].y), f2bf(b_r[3].y));
        *(short4*)&Bs[swzB(bn + 2, bk)] = make_short4(f2bf(b_r[0].z), f2bf(b_r[1].z), f2bf(b_r[2].z), f2bf(b_r[3].z));
        *(short4*)&Bs[swzB(bn + 3, bk)] = make_short4(f2bf(b_r[0].w), f2bf(b_r[1].w), f2bf(b_r[2].w), f2bf(b_r[3].w));
        lds_barrier();
        bool more = (k0 + 64) < HID;
        if (more) {
            a_r0 = *(const bf16x8*)(Asrc0 + k0 + 64);
            a_r1 = *(const bf16x8*)(Asrc1 + k0 + 64);
#pragma unroll
            for (int i = 0; i < 4; i++) b_r[i] = *(const float4*)(Bg + (size_t)(k0 + 64 + bk + i) * D + bn);
        }
#pragma unroll
        for (int kk = 0; kk < 64; kk += 32) {
            int krd = kk + 8 * (lane >> 4);
            bf16x8 a0 = *(const bf16x8*)&As[swzB(wr * 32 + (lane & 15), krd)];
            bf16x8 a1 = *(const bf16x8*)&As[swzB(wr * 32 + 16 + (lane & 15), krd)];
            bf16x8 b0 = *(const bf16x8*)&Bs[swzB(wc * 32 + (lane & 15), krd)];
            bf16x8 b1 = *(const bf16x8*)&Bs[swzB(wc * 32 + 16 + (lane & 15), krd)];
            acc[0][0] = __builtin_amdgcn_mfma_f32_16x16x32_bf16(a0, b0, acc[0][0], 0, 0, 0);
            acc[0][1] = __builtin_amdgcn_mfma_f32_16x16x32_bf16(a0, b1, acc[0][1], 0, 0, 0);
            acc[1][0] = __builtin_amdgcn_mfma_f32_16x16x32_bf16(a1, b0, acc[1][0], 0, 0, 0);
            acc[1][1] = __builtin_amdgcn_mfma_f32_16x16x32_bf16(a1, b1, acc[1][1], 0, 0, 0);
        }
        lds_barrier();
    }
#pragma unroll
    for (int mi2 = 0; mi2 < 2; mi2++)
#pragma unroll
        for (int ni = 0; ni < 2; ni++)
#pragma unroll
            for (int r = 0; r < 4; r++) {
                int row = wr * 32 + mi2 * 16 + (lane >> 4) * 4 + r;
                if (mb + row < n) {
                    int pid = rowpid[row];
                    int col = nb + wc * 32 + ni * 16 + (lane & 15);
                    yp[(size_t)pid * D + col] = acc[mi2][ni][r];
                }
            }
}

// ---------------- final combine (unchanged) ----------------
__global__ void combine_kernel(const float* __restrict__ yp, const float* __restrict__ wtok,
                               float* __restrict__ out) {
    int idx = blockIdx.x * 256 + threadIdx.x; // T * (D/4)
    if (idx >= T * (D / 4)) return;
    int t = idx / (D / 4);
    int d4 = idx % (D / 4);
    float4 a = ((const float4*)(out + (size_t)t * D))[d4];
    float4 y0 = ((const float4*)(yp + (size_t)(2 * t) * D))[d4];
    float4 y1 = ((const float4*)(yp + (size_t)(2 * t + 1) * D))[d4];
    float w0 = wtok[2 * t], w1 = wtok[2 * t + 1];
    a.x += w0 * y0.x + w1 * y1.x;
    a.y += w0 * y0.y + w1 * y1.y;
    a.z += w0 * y0.z + w1 * y1.z;
    a.w += w0 * y0.w + w1 * y1.w;
    ((float4*)(out + (size_t)t * D))[d4] = a;
}

extern "C" void kernel_launch(void* const* d_in, const int* in_sizes, int n_in,
                              void* d_out, int out_size, void* d_ws, size_t ws_size,
                              hipStream_t stream) {
    const float* x    = (const float*)d_in[0];
    const float* n1w  = (const float*)d_in[1];
    const float* n2w  = (const float*)d_in[2];
    const float* wq   = (const float*)d_in[3];
    const float* wdkv = (const float*)d_in[4];
    const float* wuk  = (const float*)d_in[5];
    const float* wuv  = (const float*)d_in[6];
    const float* wo   = (const float*)d_in[7];
    const float* gw   = (const float*)d_in[8];
    const float* w1   = (const float*)d_in[9];
    const float* w2   = (const float*)d_in[10];
    const float* w3   = (const float*)d_in[11];
    const int*   sp   = (const int*)d_in[12];
    float* out = (float*)d_out;

    // ws layout (floats). ~27.1 MB total.
    float* ws = (float*)d_ws;
    float* A_  = ws + 0;                 // 786432: qb, later h2b(fp32)
    float* B_  = ws + 786432;            // 786432: kb, later yp[0..]
    float* C_  = ws + 1572864;           // 786432: vb, later yp[..]
    float* Dd  = ws + 2359296;           // 786432: h, later ab
    float* cb  = ws + 3145728;           // 65536
    float* probs = ws + 3211264;         // 8192
    float* wtok  = ws + 3219456;         // 2048
    int*   list  = (int*)(ws + 3221504); // 8192 ints
    int*   counts= (int*)(ws + 3229696); // 16 ints
    int*   m2e_u = (int*)(ws + 3229712); // 32 ints
    int*   m2mb_u= (int*)(ws + 3229744); // 32 ints
    int*   m2e_d = (int*)(ws + 3229776); // 64 ints
    int*   m2mb_d= (int*)(ws + 3229840); // 64 ints
    int*   ntm   = (int*)(ws + 3229904); // 16 ints
    short* h2b   = (short*)(ws + 3229920);   // T*D bf16 = 1.5 MB
    short* gch   = (short*)(ws + 3623136);   // 2T*HID bf16 = 12.58 MB
    float* yp = B_;                      // 2T*D fp32 (B_ and C_ contiguous)

    hipMemsetAsync(counts, 0, 16 * sizeof(int), stream);

    // ---- attention ----
    rmsnorm_kernel<<<T, 256, 0, stream>>>(x, n1w, Dd, h2b);                                  // h
    gemm_bf16<false><<<dim3(D / 64, T / 64), 256, 0, stream>>>(Dd, wq, nullptr, A_, T, D, D);    // qb
    gemm_bf16<false><<<dim3(1, T / 64), 256, 0, stream>>>(Dd, wdkv, nullptr, cb, T, DL, D);      // c
    gemm_kuv<<<dim3(D / 64, T / 64), 256, 0, stream>>>(cb, wuk, wuv, B_, C_, T, D, DL);          // kb, vb
    rope_kernel<<<(T * H * 32 + 255) / 256, 256, 0, stream>>>(A_, B_, sp);
    attn_mfma<<<dim3(8, H, BATCH), 256, 0, stream>>>(A_, B_, C_, Dd);                        // ab
    gemm_bf16<true><<<dim3(D / 64, T / 64), 256, 0, stream>>>(Dd, wo, x, out, T, D, D);      // x1 in out

    // ---- MoE ----
    rmsnorm_kernel<<<T, 256, 0, stream>>>(out, n2w, A_, h2b);                                // h2 (fp32 + bf16)
    routing_kernel<<<T, 64, 0, stream>>>(A_, gw, probs, list, counts, wtok);
    moe_setup_kernel<<<1, 64, 0, stream>>>(counts, m2e_u, m2mb_u, m2e_d, m2mb_d, ntm);
    aux_kernel<<<1, 256, 0, stream>>>(probs, counts, out + (out_size - 1));
    moe_up_mfma<<<dim3(HID / 64, 32), 256, 0, stream>>>(h2b, w1, w3, list, counts, m2e_u, m2mb_u, ntm, gch);
    moe_down_mfma<<<dim3(D / 64, 40), 256, 0, stream>>>(gch, w2, list, counts, m2e_d, m2mb_d, ntm, yp);
    combine_kernel<<<(T * (D / 4) + 255) / 256, 256, 0, stream>>>(yp, wtok, out);
}

// Round 20
// 249.154 us; speedup vs baseline: 1.0295x; 1.0295x over previous
//
#include <hip/hip_runtime.h>
#include <hip/hip_bf16.h>
#include <math.h>

#define T 1024
#define SEQ 512
#define BATCH 2
#define D 768
#define H 12
#define DH 64
#define DL 64
#define E 8
#define HID 3072

typedef __attribute__((ext_vector_type(8))) short bf16x8;
typedef __attribute__((ext_vector_type(4))) float f32x4;

__device__ inline short f2bf(float f) {
    __hip_bfloat16 h = __float2bfloat16(f);
    return *reinterpret_cast<short*>(&h);
}

// LDS-only barrier: publishes ds ops without draining in-flight global loads.
__device__ inline void lds_barrier() {
    __builtin_amdgcn_sched_barrier(0);
    asm volatile("s_waitcnt lgkmcnt(0)" ::: "memory");
    __builtin_amdgcn_s_barrier();
    __builtin_amdgcn_sched_barrier(0);
}

// attn swizzle (validated)
__device__ inline int swz(int row, int k) { return (row * 64 + k) ^ ((row & 7) << 3); }
// GEMM swizzle (validated R9/R10)
__device__ inline int swzB(int row, int k) { return row * 64 + (k ^ (((row >> 1) & 7) << 3)); }

// ---------------- rmsnorm (dual fp32 + bf16 output) ----------------
__global__ void rmsnorm_kernel(const float* __restrict__ x, const float* __restrict__ w,
                               float* __restrict__ out, short* __restrict__ outb) {
    int t = blockIdx.x;
    int tid = threadIdx.x; // 256
    const float* xr = x + (size_t)t * D;
    float s = 0.f;
    for (int i = tid; i < D; i += 256) { float v = xr[i]; s += v * v; }
    __shared__ float red[256];
    red[tid] = s; __syncthreads();
    for (int o = 128; o > 0; o >>= 1) { if (tid < o) red[tid] += red[tid + o]; __syncthreads(); }
    float scale = 1.0f / sqrtf(red[0] / (float)D + 1e-6f);
    for (int i = tid; i < D; i += 256) {
        float v = xr[i] * scale * w[i];
        out[(size_t)t * D + i] = v;
        outb[(size_t)t * D + i] = f2bf(v);
    }
}

// ---------------- dense bf16 MFMA GEMM: R17 load-after-barrier pipeline ----------------
template<bool RES>
__global__ __launch_bounds__(256) void gemm_bf16(
    const float* __restrict__ A, const float* __restrict__ B,
    const float* __restrict__ Rp, float* __restrict__ C,
    int M, int N, int K) {
    int mb = blockIdx.y * 64, nb = blockIdx.x * 64;
    __shared__ short As[64 * 64];
    __shared__ short Bs[64 * 64];
    int tid = threadIdx.x;
    int lane = tid & 63, wave = tid >> 6;
    int wr = wave >> 1, wc = wave & 1;
    f32x4 acc[2][2] = {};
    int ar = tid >> 2, ac = (tid & 3) * 16;
    int bn = (tid & 15) * 4, bk = (tid >> 4) * 4;
    const float* Arow = A + (size_t)(mb + ar) * K + ac;
    const float* Bg = B + nb;
    float4 a_r[4], b_r[4];
#pragma unroll
    for (int j = 0; j < 4; j++) a_r[j] = *(const float4*)(Arow + j * 4);
#pragma unroll
    for (int i = 0; i < 4; i++) b_r[i] = *(const float4*)(Bg + (size_t)(bk + i) * N + bn);
    for (int k0 = 0; k0 < K; k0 += 64) {
        // write current regs to LDS
#pragma unroll
        for (int j = 0; j < 4; j++)
            *(short4*)&As[swzB(ar, ac + j * 4)] =
                make_short4(f2bf(a_r[0 + j].x), f2bf(a_r[0 + j].y), f2bf(a_r[0 + j].z), f2bf(a_r[0 + j].w));
        *(short4*)&Bs[swzB(bn + 0, bk)] = make_short4(f2bf(b_r[0].x), f2bf(b_r[1].x), f2bf(b_r[2].x), f2bf(b_r[3].x));
        *(short4*)&Bs[swzB(bn + 1, bk)] = make_short4(f2bf(b_r[0].y), f2bf(b_r[1].y), f2bf(b_r[2].y), f2bf(b_r[3].y));
        *(short4*)&Bs[swzB(bn + 2, bk)] = make_short4(f2bf(b_r[0].z), f2bf(b_r[1].z), f2bf(b_r[2].z), f2bf(b_r[3].z));
        *(short4*)&Bs[swzB(bn + 3, bk)] = make_short4(f2bf(b_r[0].w), f2bf(b_r[1].w), f2bf(b_r[2].w), f2bf(b_r[3].w));
        __syncthreads();
        // issue next-iter loads into the now-free regs; latency hides under MFMA
        bool more = (k0 + 64) < K;
        if (more) {
#pragma unroll
            for (int j = 0; j < 4; j++) a_r[j] = *(const float4*)(Arow + k0 + 64 + j * 4);
#pragma unroll
            for (int i = 0; i < 4; i++) b_r[i] = *(const float4*)(Bg + (size_t)(k0 + 64 + bk + i) * N + bn);
        }
#pragma unroll
        for (int kk = 0; kk < 64; kk += 32) {
            int krd = kk + 8 * (lane >> 4);
            bf16x8 a0 = *(const bf16x8*)&As[swzB(wr * 32 + (lane & 15), krd)];
            bf16x8 a1 = *(const bf16x8*)&As[swzB(wr * 32 + 16 + (lane & 15), krd)];
            bf16x8 b0 = *(const bf16x8*)&Bs[swzB(wc * 32 + (lane & 15), krd)];
            bf16x8 b1 = *(const bf16x8*)&Bs[swzB(wc * 32 + 16 + (lane & 15), krd)];
            acc[0][0] = __builtin_amdgcn_mfma_f32_16x16x32_bf16(a0, b0, acc[0][0], 0, 0, 0);
            acc[0][1] = __builtin_amdgcn_mfma_f32_16x16x32_bf16(a0, b1, acc[0][1], 0, 0, 0);
            acc[1][0] = __builtin_amdgcn_mfma_f32_16x16x32_bf16(a1, b0, acc[1][0], 0, 0, 0);
            acc[1][1] = __builtin_amdgcn_mfma_f32_16x16x32_bf16(a1, b1, acc[1][1], 0, 0, 0);
        }
        __syncthreads();
    }
#pragma unroll
    for (int mi = 0; mi < 2; mi++)
#pragma unroll
        for (int ni = 0; ni < 2; ni++)
#pragma unroll
            for (int r = 0; r < 4; r++) {
                int row = mb + wr * 32 + mi * 16 + (lane >> 4) * 4 + r;
                int col = nb + wc * 32 + ni * 16 + (lane & 15);
                float val = acc[mi][ni][r];
                if (RES) val += Rp[(size_t)row * N + col];
                C[(size_t)row * N + col] = val;
            }
}

// ---- fused K/V up-projection (K=64 single step — unchanged, validated) ----
__global__ __launch_bounds__(256) void gemm_kuv(
    const float* __restrict__ A, const float* __restrict__ Bk, const float* __restrict__ Bv,
    float* __restrict__ Ck, float* __restrict__ Cv, int M, int N, int K) {
    int mb = blockIdx.y * 64, nb = blockIdx.x * 64;
    __shared__ short As[64 * 64];
    __shared__ short B1s[64 * 64];
    __shared__ short B2s[64 * 64];
    int tid = threadIdx.x;
    int lane = tid & 63, wave = tid >> 6;
    int wr = wave >> 1, wc = wave & 1;
    f32x4 acc1[2][2] = {};
    f32x4 acc2[2][2] = {};
    int ar = tid >> 2, ac = (tid & 3) * 16;
    int bn = (tid & 15) * 4, bk = (tid >> 4) * 4;
    const float* Arow = A + (size_t)(mb + ar) * K + ac;
    {
        float4 a_c[4], p_c[4], q_c[4];
#pragma unroll
        for (int j = 0; j < 4; j++) a_c[j] = *(const float4*)(Arow + j * 4);
#pragma unroll
        for (int i = 0; i < 4; i++) {
            p_c[i] = *(const float4*)(Bk + (size_t)(bk + i) * N + nb + bn);
            q_c[i] = *(const float4*)(Bv + (size_t)(bk + i) * N + nb + bn);
        }
#pragma unroll
        for (int j = 0; j < 4; j++)
            *(short4*)&As[swzB(ar, ac + j * 4)] =
                make_short4(f2bf(a_c[j].x), f2bf(a_c[j].y), f2bf(a_c[j].z), f2bf(a_c[j].w));
        *(short4*)&B1s[swzB(bn + 0, bk)] = make_short4(f2bf(p_c[0].x), f2bf(p_c[1].x), f2bf(p_c[2].x), f2bf(p_c[3].x));
        *(short4*)&B1s[swzB(bn + 1, bk)] = make_short4(f2bf(p_c[0].y), f2bf(p_c[1].y), f2bf(p_c[2].y), f2bf(p_c[3].y));
        *(short4*)&B1s[swzB(bn + 2, bk)] = make_short4(f2bf(p_c[0].z), f2bf(p_c[1].z), f2bf(p_c[2].z), f2bf(p_c[3].z));
        *(short4*)&B1s[swzB(bn + 3, bk)] = make_short4(f2bf(p_c[0].w), f2bf(p_c[1].w), f2bf(p_c[2].w), f2bf(p_c[3].w));
        *(short4*)&B2s[swzB(bn + 0, bk)] = make_short4(f2bf(q_c[0].x), f2bf(q_c[1].x), f2bf(q_c[2].x), f2bf(q_c[3].x));
        *(short4*)&B2s[swzB(bn + 1, bk)] = make_short4(f2bf(q_c[0].y), f2bf(q_c[1].y), f2bf(q_c[2].y), f2bf(q_c[3].y));
        *(short4*)&B2s[swzB(bn + 2, bk)] = make_short4(f2bf(q_c[0].z), f2bf(q_c[1].z), f2bf(q_c[2].z), f2bf(q_c[3].z));
        *(short4*)&B2s[swzB(bn + 3, bk)] = make_short4(f2bf(q_c[0].w), f2bf(q_c[1].w), f2bf(q_c[2].w), f2bf(q_c[3].w));
    }
    __syncthreads();
#pragma unroll
    for (int kk = 0; kk < 64; kk += 32) {
        int krd = kk + 8 * (lane >> 4);
        bf16x8 a0 = *(const bf16x8*)&As[swzB(wr * 32 + (lane & 15), krd)];
        bf16x8 a1 = *(const bf16x8*)&As[swzB(wr * 32 + 16 + (lane & 15), krd)];
        bf16x8 p0 = *(const bf16x8*)&B1s[swzB(wc * 32 + (lane & 15), krd)];
        bf16x8 p1 = *(const bf16x8*)&B1s[swzB(wc * 32 + 16 + (lane & 15), krd)];
        bf16x8 q0 = *(const bf16x8*)&B2s[swzB(wc * 32 + (lane & 15), krd)];
        bf16x8 q1 = *(const bf16x8*)&B2s[swzB(wc * 32 + 16 + (lane & 15), krd)];
        acc1[0][0] = __builtin_amdgcn_mfma_f32_16x16x32_bf16(a0, p0, acc1[0][0], 0, 0, 0);
        acc1[0][1] = __builtin_amdgcn_mfma_f32_16x16x32_bf16(a0, p1, acc1[0][1], 0, 0, 0);
        acc1[1][0] = __builtin_amdgcn_mfma_f32_16x16x32_bf16(a1, p0, acc1[1][0], 0, 0, 0);
        acc1[1][1] = __builtin_amdgcn_mfma_f32_16x16x32_bf16(a1, p1, acc1[1][1], 0, 0, 0);
        acc2[0][0] = __builtin_amdgcn_mfma_f32_16x16x32_bf16(a0, q0, acc2[0][0], 0, 0, 0);
        acc2[0][1] = __builtin_amdgcn_mfma_f32_16x16x32_bf16(a0, q1, acc2[0][1], 0, 0, 0);
        acc2[1][0] = __builtin_amdgcn_mfma_f32_16x16x32_bf16(a1, q0, acc2[1][0], 0, 0, 0);
        acc2[1][1] = __builtin_amdgcn_mfma_f32_16x16x32_bf16(a1, q1, acc2[1][1], 0, 0, 0);
    }
#pragma unroll
    for (int mi = 0; mi < 2; mi++)
#pragma unroll
        for (int ni = 0; ni < 2; ni++)
#pragma unroll
            for (int r = 0; r < 4; r++) {
                int row = mb + wr * 32 + mi * 16 + (lane >> 4) * 4 + r;
                int col = nb + wc * 32 + ni * 16 + (lane & 15);
                Ck[(size_t)row * N + col] = acc1[mi][ni][r];
                Cv[(size_t)row * N + col] = acc2[mi][ni][r];
            }
}

// ---------------- RoPE (unchanged) ----------------
__global__ void rope_kernel(float* __restrict__ qb, float* __restrict__ kb,
                            const int* __restrict__ spp) {
    int p = blockIdx.x * 256 + threadIdx.x; // T*H*32
    if (p >= T * H * 32) return;
    int i = p & 31;
    int rem = p >> 5;
    int h = rem % H;
    int ts = rem / H;
    int s = ts % SEQ;
    float invf = powf(10000.0f, -(float)(2 * i) / 64.0f);
    float ang = (float)(s + spp[0]) * invf;
    float c = cosf(ang), sn = sinf(ang);
    size_t base = (size_t)ts * D + h * DH;
    float x1 = qb[base + i], x2 = qb[base + 32 + i];
    qb[base + i] = x1 * c - x2 * sn;
    qb[base + 32 + i] = x1 * sn + x2 * c;
    x1 = kb[base + i]; x2 = kb[base + 32 + i];
    kb[base + i] = x1 * c - x2 * sn;
    kb[base + 32 + i] = x1 * sn + x2 * c;
}

// ---------------- flash attention (unchanged) ----------------
__global__ __launch_bounds__(256) void attn_mfma(
    const float* __restrict__ q, const float* __restrict__ k,
    const float* __restrict__ v, float* __restrict__ a) {
    int qt = blockIdx.x, h = blockIdx.y, b = blockIdx.z;
    int tid = threadIdx.x, lane = tid & 63, wave = tid >> 6;
    __shared__ short Qs[64 * 64];
    __shared__ short Ks[64 * 64];
    __shared__ short Vs[64 * 64];
    __shared__ short Ps[64 * 64];
    int qbase = qt * 64;
    {
        int r = tid >> 2, d0 = (tid & 3) * 16;
        const float* src = q + ((size_t)(b * SEQ + qbase + r)) * D + h * DH + d0;
#pragma unroll
        for (int j = 0; j < 4; j++) {
            float4 vv = *(const float4*)(src + j * 4);
            *(short4*)&Qs[swz(r, d0 + j * 4)] =
                make_short4(f2bf(vv.x), f2bf(vv.y), f2bf(vv.z), f2bf(vv.w));
        }
    }
    __syncthreads();
    bf16x8 qf0 = *(const bf16x8*)&Qs[swz(wave * 16 + (lane & 15), 8 * (lane >> 4))];
    bf16x8 qf1 = *(const bf16x8*)&Qs[swz(wave * 16 + (lane & 15), 32 + 8 * (lane >> 4))];

    float m_run[4] = {-1e30f, -1e30f, -1e30f, -1e30f};
    float l_run[4] = {0.f, 0.f, 0.f, 0.f};
    f32x4 o[4] = {};

    for (int kt = 0; kt <= qt; kt++) {
        int kvbase = kt * 64;
        {
            int r = tid >> 2, d0 = (tid & 3) * 16;
            const float* src = k + ((size_t)(b * SEQ + kvbase + r)) * D + h * DH + d0;
#pragma unroll
            for (int j = 0; j < 4; j++) {
                float4 vv = *(const float4*)(src + j * 4);
                *(short4*)&Ks[swz(r, d0 + j * 4)] =
                    make_short4(f2bf(vv.x), f2bf(vv.y), f2bf(vv.z), f2bf(vv.w));
            }
        }
#pragma unroll
        for (int i = 0; i < 4; i++) {
            int idx = tid + i * 256;
            int kr = idx >> 4, d0 = (idx & 15) * 4;
            float4 vv = *(const float4*)(v + ((size_t)(b * SEQ + kvbase + kr)) * D + h * DH + d0);
            Vs[swz(d0 + 0, kr)] = f2bf(vv.x); Vs[swz(d0 + 1, kr)] = f2bf(vv.y);
            Vs[swz(d0 + 2, kr)] = f2bf(vv.z); Vs[swz(d0 + 3, kr)] = f2bf(vv.w);
        }
        __syncthreads();

        f32x4 s[4];
#pragma unroll
        for (int kvt = 0; kvt < 4; kvt++) {
            bf16x8 kf0 = *(const bf16x8*)&Ks[swz(kvt * 16 + (lane & 15), 8 * (lane >> 4))];
            bf16x8 kf1 = *(const bf16x8*)&Ks[swz(kvt * 16 + (lane & 15), 32 + 8 * (lane >> 4))];
            f32x4 z = {};
            z = __builtin_amdgcn_mfma_f32_16x16x32_bf16(qf0, kf0, z, 0, 0, 0);
            z = __builtin_amdgcn_mfma_f32_16x16x32_bf16(qf1, kf1, z, 0, 0, 0);
            s[kvt] = z;
        }
#pragma unroll
        for (int kvt = 0; kvt < 4; kvt++) {
#pragma unroll
            for (int r = 0; r < 4; r++) {
                float val = s[kvt][r] * 0.125f;
                if (kt == qt) {
                    int kv_abs = kvbase + kvt * 16 + (lane & 15);
                    int q_abs = qbase + wave * 16 + (lane >> 4) * 4 + r;
                    if (kv_abs > q_abs) val = -1e30f;
                }
                s[kvt][r] = val;
            }
        }
        float mnew[4], psum[4], scl[4];
#pragma unroll
        for (int r = 0; r < 4; r++) {
            float mx = fmaxf(fmaxf(s[0][r], s[1][r]), fmaxf(s[2][r], s[3][r]));
#pragma unroll
            for (int o2 = 8; o2 > 0; o2 >>= 1) mx = fmaxf(mx, __shfl_xor(mx, o2));
            mnew[r] = fmaxf(m_run[r], mx);
            float ps = 0.f;
#pragma unroll
            for (int kvt = 0; kvt < 4; kvt++) {
                float p = expf(s[kvt][r] - mnew[r]);
                s[kvt][r] = p;
                ps += p;
            }
#pragma unroll
            for (int o2 = 8; o2 > 0; o2 >>= 1) ps += __shfl_xor(ps, o2);
            psum[r] = ps;
            scl[r] = expf(m_run[r] - mnew[r]);
            m_run[r] = mnew[r];
            l_run[r] = l_run[r] * scl[r] + psum[r];
        }
#pragma unroll
        for (int dt = 0; dt < 4; dt++)
#pragma unroll
            for (int r = 0; r < 4; r++) o[dt][r] *= scl[r];
#pragma unroll
        for (int kvt = 0; kvt < 4; kvt++)
#pragma unroll
            for (int r = 0; r < 4; r++)
                Ps[swz(wave * 16 + (lane >> 4) * 4 + r, kvt * 16 + (lane & 15))] = f2bf(s[kvt][r]);
        __syncthreads();
        bf16x8 pa0 = *(const bf16x8*)&Ps[swz(wave * 16 + (lane & 15), 8 * (lane >> 4))];
        bf16x8 pa1 = *(const bf16x8*)&Ps[swz(wave * 16 + (lane & 15), 32 + 8 * (lane >> 4))];
#pragma unroll
        for (int dt = 0; dt < 4; dt++) {
            bf16x8 vf0 = *(const bf16x8*)&Vs[swz(dt * 16 + (lane & 15), 8 * (lane >> 4))];
            bf16x8 vf1 = *(const bf16x8*)&Vs[swz(dt * 16 + (lane & 15), 32 + 8 * (lane >> 4))];
            o[dt] = __builtin_amdgcn_mfma_f32_16x16x32_bf16(pa0, vf0, o[dt], 0, 0, 0);
            o[dt] = __builtin_amdgcn_mfma_f32_16x16x32_bf16(pa1, vf1, o[dt], 0, 0, 0);
        }
        __syncthreads();
    }
#pragma unroll
    for (int r = 0; r < 4; r++) {
        float inv = 1.0f / l_run[r];
        int qrow = qbase + wave * 16 + (lane >> 4) * 4 + r;
#pragma unroll
        for (int dt = 0; dt < 4; dt++) {
            a[((size_t)(b * SEQ + qrow)) * D + h * DH + dt * 16 + (lane & 15)] = o[dt][r] * inv;
        }
    }
}

// ---------------- routing (unchanged) ----------------
__global__ void routing_kernel(const float* __restrict__ h2, const float* __restrict__ gw,
                               float* __restrict__ probs, int* __restrict__ list,
                               int* __restrict__ counts, float* __restrict__ wtok) {
    int t = blockIdx.x;
    int tid = threadIdx.x; // 64
    __shared__ float part[64][8];
    float l[8] = {0.f, 0.f, 0.f, 0.f, 0.f, 0.f, 0.f, 0.f};
    const float* hr = h2 + (size_t)t * D;
    for (int i = tid; i < D; i += 64) {
        float hv = hr[i];
        const float* g = gw + (size_t)i * E;
#pragma unroll
        for (int e = 0; e < 8; e++) l[e] += hv * g[e];
    }
#pragma unroll
    for (int e = 0; e < 8; e++) part[tid][e] = l[e];
    __syncthreads();
    if (tid == 0) {
        float lg[8];
#pragma unroll
        for (int e = 0; e < 8; e++) {
            float s = 0.f;
            for (int j = 0; j < 64; j++) s += part[j][e];
            lg[e] = s;
        }
        float m = lg[0];
#pragma unroll
        for (int e = 1; e < 8; e++) m = fmaxf(m, lg[e]);
        float se = 0.f;
        float pr[8];
#pragma unroll
        for (int e = 0; e < 8; e++) { pr[e] = expf(lg[e] - m); se += pr[e]; }
#pragma unroll
        for (int e = 0; e < 8; e++) { pr[e] /= se; probs[t * 8 + e] = pr[e]; }
        int i0 = 0;
#pragma unroll
        for (int e = 1; e < 8; e++) if (pr[e] > pr[i0]) i0 = e;
        int i1 = -1;
#pragma unroll
        for (int e = 0; e < 8; e++) {
            if (e == i0) continue;
            if (i1 < 0 || pr[e] > pr[i1]) i1 = e;
        }
        float w0 = pr[i0], w1 = pr[i1];
        float wsum = w0 + w1;
        wtok[t * 2 + 0] = w0 / wsum;
        wtok[t * 2 + 1] = w1 / wsum;
        int p0 = atomicAdd(&counts[i0], 1); list[i0 * T + p0] = t * 2 + 0;
        int p1 = atomicAdd(&counts[i1], 1); list[i1 * T + p1] = t * 2 + 1;
    }
}

// ---- MoE tile-map setup (unchanged) ----
__global__ void moe_setup_kernel(const int* __restrict__ counts,
                                 int* __restrict__ m2e_u, int* __restrict__ m2mb_u,
                                 int* __restrict__ m2e_d, int* __restrict__ m2mb_d,
                                 int* __restrict__ ntm) {
    if (threadIdx.x == 0 && blockIdx.x == 0) {
        int idx = 0;
        for (int e = 0; e < E; e++) {
            int nt = (counts[e] + 127) >> 7;
            for (int i = 0; i < nt; i++) { m2e_u[idx] = e; m2mb_u[idx] = i * 128; idx++; }
        }
        ntm[0] = idx;
        idx = 0;
        for (int e = 0; e < E; e++) {
            int nt = (counts[e] + 63) >> 6;
            for (int i = 0; i < nt; i++) { m2e_d[idx] = e; m2mb_d[idx] = i * 64; idx++; }
        }
        ntm[1] = idx;
    }
}

// ---------------- aux loss (unchanged) ----------------
__global__ void aux_kernel(const float* __restrict__ probs, const int* __restrict__ counts,
                           float* __restrict__ out_aux) {
    int tid = threadIdx.x;
    __shared__ float ps[8];
    if (tid < 8) {
        float s = 0.f;
        for (int t = 0; t < T; t++) s += probs[t * 8 + tid];
        ps[tid] = s;
    }
    __syncthreads();
    if (tid == 0) {
        float aux = 0.f;
        for (int e = 0; e < 8; e++) {
            float f = (float)counts[e] / (float)T;
            float P = ps[e] / (float)T;
            aux += f * P;
        }
        out_aux[0] = (float)E * aux;
    }
}

// ---- MoE up: BM=128 x BN=64, bf16 A, LDS dbuf + lds_barrier (R19, validated) ----
__global__ __launch_bounds__(256) void moe_up_mfma(
    const short* __restrict__ h2b, const float* __restrict__ w1, const float* __restrict__ w3,
    const int* __restrict__ list, const int* __restrict__ counts,
    const int* __restrict__ m2e, const int* __restrict__ m2mb, const int* __restrict__ ntm,
    short* __restrict__ g) {
    int mi = blockIdx.y;
    if (mi >= ntm[0]) return;
    int e = m2e[mi];
    int mb = m2mb[mi];
    int n = counts[e];
    int nb = blockIdx.x * 64;
    const float* B1g = w1 + (size_t)e * D * HID + nb;
    const float* B3g = w3 + (size_t)e * D * HID + nb;
    __shared__ short As[2][128 * 64];
    __shared__ short B1s[2][64 * 64];
    __shared__ short B3s[2][64 * 64];
    __shared__ int rowpid[128];
    __shared__ int rowtok[128];
    int tid = threadIdx.x;
    int lane = tid & 63, wave = tid >> 6;
    int wr = wave >> 1, wc = wave & 1;
    if (tid < 128) {
        int r = mb + tid;
        int pid = (r < n) ? list[e * T + r] : list[e * T];
        rowpid[tid] = pid;
        rowtok[tid] = pid >> 1;
    }
    __syncthreads();

    f32x4 acc1[4][2] = {};
    f32x4 acc3[4][2] = {};
    int ar = tid >> 1, ac = (tid & 1) * 32;
    int bn = (tid & 15) * 4, bk = (tid >> 4) * 4;
    const short* Arow = h2b + (size_t)rowtok[ar] * D + ac;

    bf16x8 a_r[4];
    float4 b1_r[4], b3_r[4];
    // prologue: tile0 -> regs -> buf0
#pragma unroll
    for (int j = 0; j < 4; j++) a_r[j] = *(const bf16x8*)(Arow + j * 8);
#pragma unroll
    for (int i = 0; i < 4; i++) {
        b1_r[i] = *(const float4*)(B1g + (size_t)(bk + i) * HID + bn);
        b3_r[i] = *(const float4*)(B3g + (size_t)(bk + i) * HID + bn);
    }
#pragma unroll
    for (int j = 0; j < 4; j++) *(bf16x8*)&As[0][swzB(ar, ac + j * 8)] = a_r[j];
    *(short4*)&B1s[0][swzB(bn + 0, bk)] = make_short4(f2bf(b1_r[0].x), f2bf(b1_r[1].x), f2bf(b1_r[2].x), f2bf(b1_r[3].x));
    *(short4*)&B1s[0][swzB(bn + 1, bk)] = make_short4(f2bf(b1_r[0].y), f2bf(b1_r[1].y), f2bf(b1_r[2].y), f2bf(b1_r[3].y));
    *(short4*)&B1s[0][swzB(bn + 2, bk)] = make_short4(f2bf(b1_r[0].z), f2bf(b1_r[1].z), f2bf(b1_r[2].z), f2bf(b1_r[3].z));
    *(short4*)&B1s[0][swzB(bn + 3, bk)] = make_short4(f2bf(b1_r[0].w), f2bf(b1_r[1].w), f2bf(b1_r[2].w), f2bf(b1_r[3].w));
    *(short4*)&B3s[0][swzB(bn + 0, bk)] = make_short4(f2bf(b3_r[0].x), f2bf(b3_r[1].x), f2bf(b3_r[2].x), f2bf(b3_r[3].x));
    *(short4*)&B3s[0][swzB(bn + 1, bk)] = make_short4(f2bf(b3_r[0].y), f2bf(b3_r[1].y), f2bf(b3_r[2].y), f2bf(b3_r[3].y));
    *(short4*)&B3s[0][swzB(bn + 2, bk)] = make_short4(f2bf(b3_r[0].z), f2bf(b3_r[1].z), f2bf(b3_r[2].z), f2bf(b3_r[3].z));
    *(short4*)&B3s[0][swzB(bn + 3, bk)] = make_short4(f2bf(b3_r[0].w), f2bf(b3_r[1].w), f2bf(b3_r[2].w), f2bf(b3_r[3].w));
    lds_barrier();
    // issue loads for tile1
#pragma unroll
    for (int j = 0; j < 4; j++) a_r[j] = *(const bf16x8*)(Arow + 64 + j * 8);
#pragma unroll
    for (int i = 0; i < 4; i++) {
        b1_r[i] = *(const float4*)(B1g + (size_t)(64 + bk + i) * HID + bn);
        b3_r[i] = *(const float4*)(B3g + (size_t)(64 + bk + i) * HID + bn);
    }

    int cur = 0;
    for (int k0 = 0; k0 < D; k0 += 64) {
        bool more = (k0 + 64) < D;
        if (more) {
            int nx = cur ^ 1;
#pragma unroll
            for (int j = 0; j < 4; j++) *(bf16x8*)&As[nx][swzB(ar, ac + j * 8)] = a_r[j];
            *(short4*)&B1s[nx][swzB(bn + 0, bk)] = make_short4(f2bf(b1_r[0].x), f2bf(b1_r[1].x), f2bf(b1_r[2].x), f2bf(b1_r[3].x));
            *(short4*)&B1s[nx][swzB(bn + 1, bk)] = make_short4(f2bf(b1_r[0].y), f2bf(b1_r[1].y), f2bf(b1_r[2].y), f2bf(b1_r[3].y));
            *(short4*)&B1s[nx][swzB(bn + 2, bk)] = make_short4(f2bf(b1_r[0].z), f2bf(b1_r[1].z), f2bf(b1_r[2].z), f2bf(b1_r[3].z));
            *(short4*)&B1s[nx][swzB(bn + 3, bk)] = make_short4(f2bf(b1_r[0].w), f2bf(b1_r[1].w), f2bf(b1_r[2].w), f2bf(b1_r[3].w));
            *(short4*)&B3s[nx][swzB(bn + 0, bk)] = make_short4(f2bf(b3_r[0].x), f2bf(b3_r[1].x), f2bf(b3_r[2].x), f2bf(b3_r[3].x));
            *(short4*)&B3s[nx][swzB(bn + 1, bk)] = make_short4(f2bf(b3_r[0].y), f2bf(b3_r[1].y), f2bf(b3_r[2].y), f2bf(b3_r[3].y));
            *(short4*)&B3s[nx][swzB(bn + 2, bk)] = make_short4(f2bf(b3_r[0].z), f2bf(b3_r[1].z), f2bf(b3_r[2].z), f2bf(b3_r[3].z));
            *(short4*)&B3s[nx][swzB(bn + 3, bk)] = make_short4(f2bf(b3_r[0].w), f2bf(b3_r[1].w), f2bf(b3_r[2].w), f2bf(b3_r[3].w));
        }
        if (k0 + 128 < D) {
#pragma unroll
            for (int j = 0; j < 4; j++) a_r[j] = *(const bf16x8*)(Arow + k0 + 128 + j * 8);
#pragma unroll
            for (int i = 0; i < 4; i++) {
                b1_r[i] = *(const float4*)(B1g + (size_t)(k0 + 128 + bk + i) * HID + bn);
                b3_r[i] = *(const float4*)(B3g + (size_t)(k0 + 128 + bk + i) * HID + bn);
            }
        }
#pragma unroll
        for (int kk = 0; kk < 64; kk += 32) {
            int krd = kk + 8 * (lane >> 4);
            bf16x8 b1f[2], b3f[2];
#pragma unroll
            for (int ni = 0; ni < 2; ni++) {
                b1f[ni] = *(const bf16x8*)&B1s[cur][swzB(wc * 32 + ni * 16 + (lane & 15), krd)];
                b3f[ni] = *(const bf16x8*)&B3s[cur][swzB(wc * 32 + ni * 16 + (lane & 15), krd)];
            }
#pragma unroll
            for (int mi2 = 0; mi2 < 4; mi2++) {
                bf16x8 af = *(const bf16x8*)&As[cur][swzB(wr * 64 + mi2 * 16 + (lane & 15), krd)];
                acc1[mi2][0] = __builtin_amdgcn_mfma_f32_16x16x32_bf16(af, b1f[0], acc1[mi2][0], 0, 0, 0);
                acc1[mi2][1] = __builtin_amdgcn_mfma_f32_16x16x32_bf16(af, b1f[1], acc1[mi2][1], 0, 0, 0);
                acc3[mi2][0] = __builtin_amdgcn_mfma_f32_16x16x32_bf16(af, b3f[0], acc3[mi2][0], 0, 0, 0);
                acc3[mi2][1] = __builtin_amdgcn_mfma_f32_16x16x32_bf16(af, b3f[1], acc3[mi2][1], 0, 0, 0);
            }
        }
        lds_barrier();
        cur ^= 1;
    }
#pragma unroll
    for (int mi2 = 0; mi2 < 4; mi2++)
#pragma unroll
        for (int ni = 0; ni < 2; ni++)
#pragma unroll
            for (int r = 0; r < 4; r++) {
                int row = wr * 64 + mi2 * 16 + (lane >> 4) * 4 + r;
                if (mb + row < n) {
                    int pid = rowpid[row];
                    int col = nb + wc * 32 + ni * 16 + (lane & 15);
                    float v1 = acc1[mi2][ni][r], v3 = acc3[mi2][ni][r];
                    float sil = v1 / (1.f + expf(-v1));
                    g[(size_t)pid * HID + col] = f2bf(sil * v3);
                }
            }
}

// ---- MoE down: BM=64, load-after-barrier + lds_barrier (R19, validated) ----
__global__ __launch_bounds__(256) void moe_down_mfma(
    const short* __restrict__ g, const float* __restrict__ w2,
    const int* __restrict__ list, const int* __restrict__ counts,
    const int* __restrict__ m2e, const int* __restrict__ m2mb, const int* __restrict__ ntm,
    float* __restrict__ yp) {
    int mi = blockIdx.y;
    if (mi >= ntm[1]) return;
    int e = m2e[mi];
    int mb = m2mb[mi];
    int n = counts[e];
    int nb = blockIdx.x * 64;
    const float* Bg = w2 + (size_t)e * HID * D + nb;
    __shared__ short As[64 * 64];
    __shared__ short Bs[64 * 64];
    __shared__ int rowpid[64];
    int tid = threadIdx.x;
    int lane = tid & 63, wave = tid >> 6;
    int wr = wave >> 1, wc = wave & 1;
    if (tid < 64) {
        int r = mb + tid;
        rowpid[tid] = (r < n) ? list[e * T + r] : list[e * T];
    }
    __syncthreads();

    f32x4 acc[2][2] = {};
    int ar0 = tid >> 3, ak0 = (tid & 7) * 8;
    int ar1 = (tid + 256) >> 3, ak1 = ((tid + 256) & 7) * 8;
    int bn = (tid & 15) * 4, bk = (tid >> 4) * 4;
    const short* Asrc0 = g + (size_t)rowpid[ar0] * HID + ak0;
    const short* Asrc1 = g + (size_t)rowpid[ar1] * HID + ak1;

    bf16x8 a_r0 = *(const bf16x8*)(Asrc0);
    bf16x8 a_r1 = *(const bf16x8*)(Asrc1);
    float4 b_r[4];
#pragma unroll
    for (int i = 0; i < 4; i++) b_r[i] = *(const float4*)(Bg + (size_t)(bk + i) * D + bn);

    for (int k0 = 0; k0 < HID; k0 += 64) {
        *(bf16x8*)&As[swzB(ar0, ak0)] = a_r0;
        *(bf16x8*)&As[swzB(ar1, ak1)] = a_r1;
        *(short4*)&Bs[swzB(bn + 0, bk)] = make_short4(f2bf(b_r[0].x), f2bf(b_r[1].x), f2bf(b_r[2].x), f2bf(b_r[3].x));
        *(short4*)&Bs[swzB(bn + 1, bk)] = make_short4(f2bf(b_r[0].y), f2bf(b_r[1].y), f2bf(b_r[2].y), f2bf(b_r[3].y));
        *(short4*)&Bs[swzB(bn + 2, bk)] = make_short4(f2bf(b_r[0].z), f2bf(b_r[1].z), f2bf(b_r[2].z), f2bf(b_r[3].z));
        *(short4*)&Bs[swzB(bn + 3, bk)] = make_short4(f2bf(b_r[0].w), f2bf(b_r[1].w), f2bf(b_r[2].w), f2bf(b_r[3].w));
        lds_barrier();
        bool more = (k0 + 64) < HID;
        if (more) {
            a_r0 = *(const bf16x8*)(Asrc0 + k0 + 64);
            a_r1 = *(const bf16x8*)(Asrc1 + k0 + 64);
#pragma unroll
            for (int i = 0; i < 4; i++) b_r[i] = *(const float4*)(Bg + (size_t)(k0 + 64 + bk + i) * D + bn);
        }
#pragma unroll
        for (int kk = 0; kk < 64; kk += 32) {
            int krd = kk + 8 * (lane >> 4);
            bf16x8 a0 = *(const bf16x8*)&As[swzB(wr * 32 + (lane & 15), krd)];
            bf16x8 a1 = *(const bf16x8*)&As[swzB(wr * 32 + 16 + (lane & 15), krd)];
            bf16x8 b0 = *(const bf16x8*)&Bs[swzB(wc * 32 + (lane & 15), krd)];
            bf16x8 b1 = *(const bf16x8*)&Bs[swzB(wc * 32 + 16 + (lane & 15), krd)];
            acc[0][0] = __builtin_amdgcn_mfma_f32_16x16x32_bf16(a0, b0, acc[0][0], 0, 0, 0);
            acc[0][1] = __builtin_amdgcn_mfma_f32_16x16x32_bf16(a0, b1, acc[0][1], 0, 0, 0);
            acc[1][0] = __builtin_amdgcn_mfma_f32_16x16x32_bf16(a1, b0, acc[1][0], 0, 0, 0);
            acc[1][1] = __builtin_amdgcn_mfma_f32_16x16x32_bf16(a1, b1, acc[1][1], 0, 0, 0);
        }
        lds_barrier();
    }
#pragma unroll
    for (int mi2 = 0; mi2 < 2; mi2++)
#pragma unroll
        for (int ni = 0; ni < 2; ni++)
#pragma unroll
            for (int r = 0; r < 4; r++) {
                int row = wr * 32 + mi2 * 16 + (lane >> 4) * 4 + r;
                if (mb + row < n) {
                    int pid = rowpid[row];
                    int col = nb + wc * 32 + ni * 16 + (lane & 15);
                    yp[(size_t)pid * D + col] = acc[mi2][ni][r];
                }
            }
}

// ---------------- final combine (unchanged) ----------------
__global__ void combine_kernel(const float* __restrict__ yp, const float* __restrict__ wtok,
                               float* __restrict__ out) {
    int idx = blockIdx.x * 256 + threadIdx.x; // T * (D/4)
    if (idx >= T * (D / 4)) return;
    int t = idx / (D / 4);
    int d4 = idx % (D / 4);
    float4 a = ((const float4*)(out + (size_t)t * D))[d4];
    float4 y0 = ((const float4*)(yp + (size_t)(2 * t) * D))[d4];
    float4 y1 = ((const float4*)(yp + (size_t)(2 * t + 1) * D))[d4];
    float w0 = wtok[2 * t], w1 = wtok[2 * t + 1];
    a.x += w0 * y0.x + w1 * y1.x;
    a.y += w0 * y0.y + w1 * y1.y;
    a.z += w0 * y0.z + w1 * y1.z;
    a.w += w0 * y0.w + w1 * y1.w;
    ((float4*)(out + (size_t)t * D))[d4] = a;
}

extern "C" void kernel_launch(void* const* d_in, const int* in_sizes, int n_in,
                              void* d_out, int out_size, void* d_ws, size_t ws_size,
                              hipStream_t stream) {
    const float* x    = (const float*)d_in[0];
    const float* n1w  = (const float*)d_in[1];
    const float* n2w  = (const float*)d_in[2];
    const float* wq   = (const float*)d_in[3];
    const float* wdkv = (const float*)d_in[4];
    const float* wuk  = (const float*)d_in[5];
    const float* wuv  = (const float*)d_in[6];
    const float* wo   = (const float*)d_in[7];
    const float* gw   = (const float*)d_in[8];
    const float* w1   = (const float*)d_in[9];
    const float* w2   = (const float*)d_in[10];
    const float* w3   = (const float*)d_in[11];
    const int*   sp   = (const int*)d_in[12];
    float* out = (float*)d_out;

    // ws layout (floats). ~27.1 MB total.
    float* ws = (float*)d_ws;
    float* A_  = ws + 0;                 // 786432: qb, later h2b(fp32)
    float* B_  = ws + 786432;            // 786432: kb, later yp[0..]
    float* C_  = ws + 1572864;           // 786432: vb, later yp[..]
    float* Dd  = ws + 2359296;           // 786432: h, later ab
    float* cb  = ws + 3145728;           // 65536
    float* probs = ws + 3211264;         // 8192
    float* wtok  = ws + 3219456;         // 2048
    int*   list  = (int*)(ws + 3221504); // 8192 ints
    int*   counts= (int*)(ws + 3229696); // 16 ints
    int*   m2e_u = (int*)(ws + 3229712); // 32 ints
    int*   m2mb_u= (int*)(ws + 3229744); // 32 ints
    int*   m2e_d = (int*)(ws + 3229776); // 64 ints
    int*   m2mb_d= (int*)(ws + 3229840); // 64 ints
    int*   ntm   = (int*)(ws + 3229904); // 16 ints
    short* h2b   = (short*)(ws + 3229920);   // T*D bf16 = 1.5 MB
    short* gch   = (short*)(ws + 3623136);   // 2T*HID bf16 = 12.58 MB
    float* yp = B_;                      // 2T*D fp32 (B_ and C_ contiguous)

    hipMemsetAsync(counts, 0, 16 * sizeof(int), stream);

    // ---- attention ----
    rmsnorm_kernel<<<T, 256, 0, stream>>>(x, n1w, Dd, h2b);                                  // h
    gemm_bf16<false><<<dim3(D / 64, T / 64), 256, 0, stream>>>(Dd, wq, nullptr, A_, T, D, D);    // qb
    gemm_bf16<false><<<dim3(1, T / 64), 256, 0, stream>>>(Dd, wdkv, nullptr, cb, T, DL, D);      // c
    gemm_kuv<<<dim3(D / 64, T / 64), 256, 0, stream>>>(cb, wuk, wuv, B_, C_, T, D, DL);          // kb, vb
    rope_kernel<<<(T * H * 32 + 255) / 256, 256, 0, stream>>>(A_, B_, sp);
    attn_mfma<<<dim3(8, H, BATCH), 256, 0, stream>>>(A_, B_, C_, Dd);                        // ab
    gemm_bf16<true><<<dim3(D / 64, T / 64), 256, 0, stream>>>(Dd, wo, x, out, T, D, D);      // x1 in out

    // ---- MoE ----
    rmsnorm_kernel<<<T, 256, 0, stream>>>(out, n2w, A_, h2b);                                // h2 (fp32 + bf16)
    routing_kernel<<<T, 64, 0, stream>>>(A_, gw, probs, list, counts, wtok);
    moe_setup_kernel<<<1, 64, 0, stream>>>(counts, m2e_u, m2mb_u, m2e_d, m2mb_d, ntm);
    aux_kernel<<<1, 256, 0, stream>>>(probs, counts, out + (out_size - 1));
    moe_up_mfma<<<dim3(HID / 64, 32), 256, 0, stream>>>(h2b, w1, w3, list, counts, m2e_u, m2mb_u, ntm, gch);
    moe_down_mfma<<<dim3(D / 64, 40), 256, 0, stream>>>(gch, w2, list, counts, m2e_d, m2mb_d, ntm, yp);
    combine_kernel<<<(T * (D / 4) + 255) / 256, 256, 0, stream>>>(yp, wtok, out);
}

// Round 21
// 219.854 us; speedup vs baseline: 1.1667x; 1.1333x over previous
//
#include <hip/hip_runtime.h>
#include <hip/hip_bf16.h>
#include <math.h>

#define T 1024
#define SEQ 512
#define BATCH 2
#define D 768
#define H 12
#define DH 64
#define DL 64
#define E 8
#define HID 3072

typedef __attribute__((ext_vector_type(8))) short bf16x8;
typedef __attribute__((ext_vector_type(4))) float f32x4;

__device__ inline short f2bf(float f) {
    __hip_bfloat16 h = __float2bfloat16(f);
    return *reinterpret_cast<short*>(&h);
}

// LDS-only barrier: publishes ds ops without draining in-flight global loads.
__device__ inline void lds_barrier() {
    __builtin_amdgcn_sched_barrier(0);
    asm volatile("s_waitcnt lgkmcnt(0)" ::: "memory");
    __builtin_amdgcn_s_barrier();
    __builtin_amdgcn_sched_barrier(0);
}

// attn swizzle (validated)
__device__ inline int swz(int row, int k) { return (row * 64 + k) ^ ((row & 7) << 3); }
// GEMM swizzle (validated R9/R10)
__device__ inline int swzB(int row, int k) { return row * 64 + (k ^ (((row >> 1) & 7) << 3)); }

// ---------------- rmsnorm (dual fp32 + bf16 output) ----------------
__global__ void rmsnorm_kernel(const float* __restrict__ x, const float* __restrict__ w,
                               float* __restrict__ out, short* __restrict__ outb) {
    int t = blockIdx.x;
    int tid = threadIdx.x; // 256
    const float* xr = x + (size_t)t * D;
    float s = 0.f;
    for (int i = tid; i < D; i += 256) { float v = xr[i]; s += v * v; }
    __shared__ float red[256];
    red[tid] = s; __syncthreads();
    for (int o = 128; o > 0; o >>= 1) { if (tid < o) red[tid] += red[tid + o]; __syncthreads(); }
    float scale = 1.0f / sqrtf(red[0] / (float)D + 1e-6f);
    for (int i = tid; i < D; i += 256) {
        float v = xr[i] * scale * w[i];
        out[(size_t)t * D + i] = v;
        outb[(size_t)t * D + i] = f2bf(v);
    }
}

// ---------------- dense bf16 MFMA GEMM: R17 load-after-barrier pipeline ----------------
template<bool RES>
__global__ __launch_bounds__(256) void gemm_bf16(
    const float* __restrict__ A, const float* __restrict__ B,
    const float* __restrict__ Rp, float* __restrict__ C,
    int M, int N, int K) {
    int mb = blockIdx.y * 64, nb = blockIdx.x * 64;
    __shared__ short As[64 * 64];
    __shared__ short Bs[64 * 64];
    int tid = threadIdx.x;
    int lane = tid & 63, wave = tid >> 6;
    int wr = wave >> 1, wc = wave & 1;
    f32x4 acc[2][2] = {};
    int ar = tid >> 2, ac = (tid & 3) * 16;
    int bn = (tid & 15) * 4, bk = (tid >> 4) * 4;
    const float* Arow = A + (size_t)(mb + ar) * K + ac;
    const float* Bg = B + nb;
    float4 a_r[4], b_r[4];
#pragma unroll
    for (int j = 0; j < 4; j++) a_r[j] = *(const float4*)(Arow + j * 4);
#pragma unroll
    for (int i = 0; i < 4; i++) b_r[i] = *(const float4*)(Bg + (size_t)(bk + i) * N + bn);
    for (int k0 = 0; k0 < K; k0 += 64) {
#pragma unroll
        for (int j = 0; j < 4; j++)
            *(short4*)&As[swzB(ar, ac + j * 4)] =
                make_short4(f2bf(a_r[j].x), f2bf(a_r[j].y), f2bf(a_r[j].z), f2bf(a_r[j].w));
        *(short4*)&Bs[swzB(bn + 0, bk)] = make_short4(f2bf(b_r[0].x), f2bf(b_r[1].x), f2bf(b_r[2].x), f2bf(b_r[3].x));
        *(short4*)&Bs[swzB(bn + 1, bk)] = make_short4(f2bf(b_r[0].y), f2bf(b_r[1].y), f2bf(b_r[2].y), f2bf(b_r[3].y));
        *(short4*)&Bs[swzB(bn + 2, bk)] = make_short4(f2bf(b_r[0].z), f2bf(b_r[1].z), f2bf(b_r[2].z), f2bf(b_r[3].z));
        *(short4*)&Bs[swzB(bn + 3, bk)] = make_short4(f2bf(b_r[0].w), f2bf(b_r[1].w), f2bf(b_r[2].w), f2bf(b_r[3].w));
        __syncthreads();
        bool more = (k0 + 64) < K;
        if (more) {
#pragma unroll
            for (int j = 0; j < 4; j++) a_r[j] = *(const float4*)(Arow + k0 + 64 + j * 4);
#pragma unroll
            for (int i = 0; i < 4; i++) b_r[i] = *(const float4*)(Bg + (size_t)(k0 + 64 + bk + i) * N + bn);
        }
#pragma unroll
        for (int kk = 0; kk < 64; kk += 32) {
            int krd = kk + 8 * (lane >> 4);
            bf16x8 a0 = *(const bf16x8*)&As[swzB(wr * 32 + (lane & 15), krd)];
            bf16x8 a1 = *(const bf16x8*)&As[swzB(wr * 32 + 16 + (lane & 15), krd)];
            bf16x8 b0 = *(const bf16x8*)&Bs[swzB(wc * 32 + (lane & 15), krd)];
            bf16x8 b1 = *(const bf16x8*)&Bs[swzB(wc * 32 + 16 + (lane & 15), krd)];
            acc[0][0] = __builtin_amdgcn_mfma_f32_16x16x32_bf16(a0, b0, acc[0][0], 0, 0, 0);
            acc[0][1] = __builtin_amdgcn_mfma_f32_16x16x32_bf16(a0, b1, acc[0][1], 0, 0, 0);
            acc[1][0] = __builtin_amdgcn_mfma_f32_16x16x32_bf16(a1, b0, acc[1][0], 0, 0, 0);
            acc[1][1] = __builtin_amdgcn_mfma_f32_16x16x32_bf16(a1, b1, acc[1][1], 0, 0, 0);
        }
        __syncthreads();
    }
#pragma unroll
    for (int mi = 0; mi < 2; mi++)
#pragma unroll
        for (int ni = 0; ni < 2; ni++)
#pragma unroll
            for (int r = 0; r < 4; r++) {
                int row = mb + wr * 32 + mi * 16 + (lane >> 4) * 4 + r;
                int col = nb + wc * 32 + ni * 16 + (lane & 15);
                float val = acc[mi][ni][r];
                if (RES) val += Rp[(size_t)row * N + col];
                C[(size_t)row * N + col] = val;
            }
}

// ---- fused wq + wdkv GEMM: block-uniform select of (B, C, N, nb) ----
__global__ __launch_bounds__(256) void gemm_qdkv(
    const float* __restrict__ A, const float* __restrict__ Bq, const float* __restrict__ Bd,
    float* __restrict__ Cq, float* __restrict__ Cd) {
    int bx = blockIdx.x;
    const float* Bsel; float* Csel; int N; int nb;
    if (bx < D / 64) { Bsel = Bq; Csel = Cq; N = D;  nb = bx * 64; }
    else             { Bsel = Bd; Csel = Cd; N = DL; nb = 0; }
    int mb = blockIdx.y * 64;
    __shared__ short As[64 * 64];
    __shared__ short Bs[64 * 64];
    int tid = threadIdx.x;
    int lane = tid & 63, wave = tid >> 6;
    int wr = wave >> 1, wc = wave & 1;
    f32x4 acc[2][2] = {};
    int ar = tid >> 2, ac = (tid & 3) * 16;
    int bn = (tid & 15) * 4, bk = (tid >> 4) * 4;
    const float* Arow = A + (size_t)(mb + ar) * D + ac;
    const float* Bg = Bsel + nb;
    float4 a_r[4], b_r[4];
#pragma unroll
    for (int j = 0; j < 4; j++) a_r[j] = *(const float4*)(Arow + j * 4);
#pragma unroll
    for (int i = 0; i < 4; i++) b_r[i] = *(const float4*)(Bg + (size_t)(bk + i) * N + bn);
    for (int k0 = 0; k0 < D; k0 += 64) {
#pragma unroll
        for (int j = 0; j < 4; j++)
            *(short4*)&As[swzB(ar, ac + j * 4)] =
                make_short4(f2bf(a_r[j].x), f2bf(a_r[j].y), f2bf(a_r[j].z), f2bf(a_r[j].w));
        *(short4*)&Bs[swzB(bn + 0, bk)] = make_short4(f2bf(b_r[0].x), f2bf(b_r[1].x), f2bf(b_r[2].x), f2bf(b_r[3].x));
        *(short4*)&Bs[swzB(bn + 1, bk)] = make_short4(f2bf(b_r[0].y), f2bf(b_r[1].y), f2bf(b_r[2].y), f2bf(b_r[3].y));
        *(short4*)&Bs[swzB(bn + 2, bk)] = make_short4(f2bf(b_r[0].z), f2bf(b_r[1].z), f2bf(b_r[2].z), f2bf(b_r[3].z));
        *(short4*)&Bs[swzB(bn + 3, bk)] = make_short4(f2bf(b_r[0].w), f2bf(b_r[1].w), f2bf(b_r[2].w), f2bf(b_r[3].w));
        __syncthreads();
        bool more = (k0 + 64) < D;
        if (more) {
#pragma unroll
            for (int j = 0; j < 4; j++) a_r[j] = *(const float4*)(Arow + k0 + 64 + j * 4);
#pragma unroll
            for (int i = 0; i < 4; i++) b_r[i] = *(const float4*)(Bg + (size_t)(k0 + 64 + bk + i) * N + bn);
        }
#pragma unroll
        for (int kk = 0; kk < 64; kk += 32) {
            int krd = kk + 8 * (lane >> 4);
            bf16x8 a0 = *(const bf16x8*)&As[swzB(wr * 32 + (lane & 15), krd)];
            bf16x8 a1 = *(const bf16x8*)&As[swzB(wr * 32 + 16 + (lane & 15), krd)];
            bf16x8 b0 = *(const bf16x8*)&Bs[swzB(wc * 32 + (lane & 15), krd)];
            bf16x8 b1 = *(const bf16x8*)&Bs[swzB(wc * 32 + 16 + (lane & 15), krd)];
            acc[0][0] = __builtin_amdgcn_mfma_f32_16x16x32_bf16(a0, b0, acc[0][0], 0, 0, 0);
            acc[0][1] = __builtin_amdgcn_mfma_f32_16x16x32_bf16(a0, b1, acc[0][1], 0, 0, 0);
            acc[1][0] = __builtin_amdgcn_mfma_f32_16x16x32_bf16(a1, b0, acc[1][0], 0, 0, 0);
            acc[1][1] = __builtin_amdgcn_mfma_f32_16x16x32_bf16(a1, b1, acc[1][1], 0, 0, 0);
        }
        __syncthreads();
    }
#pragma unroll
    for (int mi = 0; mi < 2; mi++)
#pragma unroll
        for (int ni = 0; ni < 2; ni++)
#pragma unroll
            for (int r = 0; r < 4; r++) {
                int row = mb + wr * 32 + mi * 16 + (lane >> 4) * 4 + r;
                int col = nb + wc * 32 + ni * 16 + (lane & 15);
                Csel[(size_t)row * N + col] = acc[mi][ni][r];
            }
}

// ---- fused K/V up-projection (K=64 single step — unchanged, validated) ----
__global__ __launch_bounds__(256) void gemm_kuv(
    const float* __restrict__ A, const float* __restrict__ Bk, const float* __restrict__ Bv,
    float* __restrict__ Ck, float* __restrict__ Cv, int M, int N, int K) {
    int mb = blockIdx.y * 64, nb = blockIdx.x * 64;
    __shared__ short As[64 * 64];
    __shared__ short B1s[64 * 64];
    __shared__ short B2s[64 * 64];
    int tid = threadIdx.x;
    int lane = tid & 63, wave = tid >> 6;
    int wr = wave >> 1, wc = wave & 1;
    f32x4 acc1[2][2] = {};
    f32x4 acc2[2][2] = {};
    int ar = tid >> 2, ac = (tid & 3) * 16;
    int bn = (tid & 15) * 4, bk = (tid >> 4) * 4;
    const float* Arow = A + (size_t)(mb + ar) * K + ac;
    {
        float4 a_c[4], p_c[4], q_c[4];
#pragma unroll
        for (int j = 0; j < 4; j++) a_c[j] = *(const float4*)(Arow + j * 4);
#pragma unroll
        for (int i = 0; i < 4; i++) {
            p_c[i] = *(const float4*)(Bk + (size_t)(bk + i) * N + nb + bn);
            q_c[i] = *(const float4*)(Bv + (size_t)(bk + i) * N + nb + bn);
        }
#pragma unroll
        for (int j = 0; j < 4; j++)
            *(short4*)&As[swzB(ar, ac + j * 4)] =
                make_short4(f2bf(a_c[j].x), f2bf(a_c[j].y), f2bf(a_c[j].z), f2bf(a_c[j].w));
        *(short4*)&B1s[swzB(bn + 0, bk)] = make_short4(f2bf(p_c[0].x), f2bf(p_c[1].x), f2bf(p_c[2].x), f2bf(p_c[3].x));
        *(short4*)&B1s[swzB(bn + 1, bk)] = make_short4(f2bf(p_c[0].y), f2bf(p_c[1].y), f2bf(p_c[2].y), f2bf(p_c[3].y));
        *(short4*)&B1s[swzB(bn + 2, bk)] = make_short4(f2bf(p_c[0].z), f2bf(p_c[1].z), f2bf(p_c[2].z), f2bf(p_c[3].z));
        *(short4*)&B1s[swzB(bn + 3, bk)] = make_short4(f2bf(p_c[0].w), f2bf(p_c[1].w), f2bf(p_c[2].w), f2bf(p_c[3].w));
        *(short4*)&B2s[swzB(bn + 0, bk)] = make_short4(f2bf(q_c[0].x), f2bf(q_c[1].x), f2bf(q_c[2].x), f2bf(q_c[3].x));
        *(short4*)&B2s[swzB(bn + 1, bk)] = make_short4(f2bf(q_c[0].y), f2bf(q_c[1].y), f2bf(q_c[2].y), f2bf(q_c[3].y));
        *(short4*)&B2s[swzB(bn + 2, bk)] = make_short4(f2bf(q_c[0].z), f2bf(q_c[1].z), f2bf(q_c[2].z), f2bf(q_c[3].z));
        *(short4*)&B2s[swzB(bn + 3, bk)] = make_short4(f2bf(q_c[0].w), f2bf(q_c[1].w), f2bf(q_c[2].w), f2bf(q_c[3].w));
    }
    __syncthreads();
#pragma unroll
    for (int kk = 0; kk < 64; kk += 32) {
        int krd = kk + 8 * (lane >> 4);
        bf16x8 a0 = *(const bf16x8*)&As[swzB(wr * 32 + (lane & 15), krd)];
        bf16x8 a1 = *(const bf16x8*)&As[swzB(wr * 32 + 16 + (lane & 15), krd)];
        bf16x8 p0 = *(const bf16x8*)&B1s[swzB(wc * 32 + (lane & 15), krd)];
        bf16x8 p1 = *(const bf16x8*)&B1s[swzB(wc * 32 + 16 + (lane & 15), krd)];
        bf16x8 q0 = *(const bf16x8*)&B2s[swzB(wc * 32 + (lane & 15), krd)];
        bf16x8 q1 = *(const bf16x8*)&B2s[swzB(wc * 32 + 16 + (lane & 15), krd)];
        acc1[0][0] = __builtin_amdgcn_mfma_f32_16x16x32_bf16(a0, p0, acc1[0][0], 0, 0, 0);
        acc1[0][1] = __builtin_amdgcn_mfma_f32_16x16x32_bf16(a0, p1, acc1[0][1], 0, 0, 0);
        acc1[1][0] = __builtin_amdgcn_mfma_f32_16x16x32_bf16(a1, p0, acc1[1][0], 0, 0, 0);
        acc1[1][1] = __builtin_amdgcn_mfma_f32_16x16x32_bf16(a1, p1, acc1[1][1], 0, 0, 0);
        acc2[0][0] = __builtin_amdgcn_mfma_f32_16x16x32_bf16(a0, q0, acc2[0][0], 0, 0, 0);
        acc2[0][1] = __builtin_amdgcn_mfma_f32_16x16x32_bf16(a0, q1, acc2[0][1], 0, 0, 0);
        acc2[1][0] = __builtin_amdgcn_mfma_f32_16x16x32_bf16(a1, q0, acc2[1][0], 0, 0, 0);
        acc2[1][1] = __builtin_amdgcn_mfma_f32_16x16x32_bf16(a1, q1, acc2[1][1], 0, 0, 0);
    }
#pragma unroll
    for (int mi = 0; mi < 2; mi++)
#pragma unroll
        for (int ni = 0; ni < 2; ni++)
#pragma unroll
            for (int r = 0; r < 4; r++) {
                int row = mb + wr * 32 + mi * 16 + (lane >> 4) * 4 + r;
                int col = nb + wc * 32 + ni * 16 + (lane & 15);
                Ck[(size_t)row * N + col] = acc1[mi][ni][r];
                Cv[(size_t)row * N + col] = acc2[mi][ni][r];
            }
}

// ---------------- RoPE (unchanged) ----------------
__global__ void rope_kernel(float* __restrict__ qb, float* __restrict__ kb,
                            const int* __restrict__ spp) {
    int p = blockIdx.x * 256 + threadIdx.x; // T*H*32
    if (p >= T * H * 32) return;
    int i = p & 31;
    int rem = p >> 5;
    int h = rem % H;
    int ts = rem / H;
    int s = ts % SEQ;
    float invf = powf(10000.0f, -(float)(2 * i) / 64.0f);
    float ang = (float)(s + spp[0]) * invf;
    float c = cosf(ang), sn = sinf(ang);
    size_t base = (size_t)ts * D + h * DH;
    float x1 = qb[base + i], x2 = qb[base + 32 + i];
    qb[base + i] = x1 * c - x2 * sn;
    qb[base + 32 + i] = x1 * sn + x2 * c;
    x1 = kb[base + i]; x2 = kb[base + 32 + i];
    kb[base + i] = x1 * c - x2 * sn;
    kb[base + 32 + i] = x1 * sn + x2 * c;
}

// ---------------- flash attention (unchanged) ----------------
__global__ __launch_bounds__(256) void attn_mfma(
    const float* __restrict__ q, const float* __restrict__ k,
    const float* __restrict__ v, float* __restrict__ a) {
    int qt = blockIdx.x, h = blockIdx.y, b = blockIdx.z;
    int tid = threadIdx.x, lane = tid & 63, wave = tid >> 6;
    __shared__ short Qs[64 * 64];
    __shared__ short Ks[64 * 64];
    __shared__ short Vs[64 * 64];
    __shared__ short Ps[64 * 64];
    int qbase = qt * 64;
    {
        int r = tid >> 2, d0 = (tid & 3) * 16;
        const float* src = q + ((size_t)(b * SEQ + qbase + r)) * D + h * DH + d0;
#pragma unroll
        for (int j = 0; j < 4; j++) {
            float4 vv = *(const float4*)(src + j * 4);
            *(short4*)&Qs[swz(r, d0 + j * 4)] =
                make_short4(f2bf(vv.x), f2bf(vv.y), f2bf(vv.z), f2bf(vv.w));
        }
    }
    __syncthreads();
    bf16x8 qf0 = *(const bf16x8*)&Qs[swz(wave * 16 + (lane & 15), 8 * (lane >> 4))];
    bf16x8 qf1 = *(const bf16x8*)&Qs[swz(wave * 16 + (lane & 15), 32 + 8 * (lane >> 4))];

    float m_run[4] = {-1e30f, -1e30f, -1e30f, -1e30f};
    float l_run[4] = {0.f, 0.f, 0.f, 0.f};
    f32x4 o[4] = {};

    for (int kt = 0; kt <= qt; kt++) {
        int kvbase = kt * 64;
        {
            int r = tid >> 2, d0 = (tid & 3) * 16;
            const float* src = k + ((size_t)(b * SEQ + kvbase + r)) * D + h * DH + d0;
#pragma unroll
            for (int j = 0; j < 4; j++) {
                float4 vv = *(const float4*)(src + j * 4);
                *(short4*)&Ks[swz(r, d0 + j * 4)] =
                    make_short4(f2bf(vv.x), f2bf(vv.y), f2bf(vv.z), f2bf(vv.w));
            }
        }
#pragma unroll
        for (int i = 0; i < 4; i++) {
            int idx = tid + i * 256;
            int kr = idx >> 4, d0 = (idx & 15) * 4;
            float4 vv = *(const float4*)(v + ((size_t)(b * SEQ + kvbase + kr)) * D + h * DH + d0);
            Vs[swz(d0 + 0, kr)] = f2bf(vv.x); Vs[swz(d0 + 1, kr)] = f2bf(vv.y);
            Vs[swz(d0 + 2, kr)] = f2bf(vv.z); Vs[swz(d0 + 3, kr)] = f2bf(vv.w);
        }
        __syncthreads();

        f32x4 s[4];
#pragma unroll
        for (int kvt = 0; kvt < 4; kvt++) {
            bf16x8 kf0 = *(const bf16x8*)&Ks[swz(kvt * 16 + (lane & 15), 8 * (lane >> 4))];
            bf16x8 kf1 = *(const bf16x8*)&Ks[swz(kvt * 16 + (lane & 15), 32 + 8 * (lane >> 4))];
            f32x4 z = {};
            z = __builtin_amdgcn_mfma_f32_16x16x32_bf16(qf0, kf0, z, 0, 0, 0);
            z = __builtin_amdgcn_mfma_f32_16x16x32_bf16(qf1, kf1, z, 0, 0, 0);
            s[kvt] = z;
        }
#pragma unroll
        for (int kvt = 0; kvt < 4; kvt++) {
#pragma unroll
            for (int r = 0; r < 4; r++) {
                float val = s[kvt][r] * 0.125f;
                if (kt == qt) {
                    int kv_abs = kvbase + kvt * 16 + (lane & 15);
                    int q_abs = qbase + wave * 16 + (lane >> 4) * 4 + r;
                    if (kv_abs > q_abs) val = -1e30f;
                }
                s[kvt][r] = val;
            }
        }
        float mnew[4], psum[4], scl[4];
#pragma unroll
        for (int r = 0; r < 4; r++) {
            float mx = fmaxf(fmaxf(s[0][r], s[1][r]), fmaxf(s[2][r], s[3][r]));
#pragma unroll
            for (int o2 = 8; o2 > 0; o2 >>= 1) mx = fmaxf(mx, __shfl_xor(mx, o2));
            mnew[r] = fmaxf(m_run[r], mx);
            float ps = 0.f;
#pragma unroll
            for (int kvt = 0; kvt < 4; kvt++) {
                float p = expf(s[kvt][r] - mnew[r]);
                s[kvt][r] = p;
                ps += p;
            }
#pragma unroll
            for (int o2 = 8; o2 > 0; o2 >>= 1) ps += __shfl_xor(ps, o2);
            psum[r] = ps;
            scl[r] = expf(m_run[r] - mnew[r]);
            m_run[r] = mnew[r];
            l_run[r] = l_run[r] * scl[r] + psum[r];
        }
#pragma unroll
        for (int dt = 0; dt < 4; dt++)
#pragma unroll
            for (int r = 0; r < 4; r++) o[dt][r] *= scl[r];
#pragma unroll
        for (int kvt = 0; kvt < 4; kvt++)
#pragma unroll
            for (int r = 0; r < 4; r++)
                Ps[swz(wave * 16 + (lane >> 4) * 4 + r, kvt * 16 + (lane & 15))] = f2bf(s[kvt][r]);
        __syncthreads();
        bf16x8 pa0 = *(const bf16x8*)&Ps[swz(wave * 16 + (lane & 15), 8 * (lane >> 4))];
        bf16x8 pa1 = *(const bf16x8*)&Ps[swz(wave * 16 + (lane & 15), 32 + 8 * (lane >> 4))];
#pragma unroll
        for (int dt = 0; dt < 4; dt++) {
            bf16x8 vf0 = *(const bf16x8*)&Vs[swz(dt * 16 + (lane & 15), 8 * (lane >> 4))];
            bf16x8 vf1 = *(const bf16x8*)&Vs[swz(dt * 16 + (lane & 15), 32 + 8 * (lane >> 4))];
            o[dt] = __builtin_amdgcn_mfma_f32_16x16x32_bf16(pa0, vf0, o[dt], 0, 0, 0);
            o[dt] = __builtin_amdgcn_mfma_f32_16x16x32_bf16(pa1, vf1, o[dt], 0, 0, 0);
        }
        __syncthreads();
    }
#pragma unroll
    for (int r = 0; r < 4; r++) {
        float inv = 1.0f / l_run[r];
        int qrow = qbase + wave * 16 + (lane >> 4) * 4 + r;
#pragma unroll
        for (int dt = 0; dt < 4; dt++) {
            a[((size_t)(b * SEQ + qrow)) * D + h * DH + dt * 16 + (lane & 15)] = o[dt][r] * inv;
        }
    }
}

// ---------------- routing (unchanged) ----------------
__global__ void routing_kernel(const float* __restrict__ h2, const float* __restrict__ gw,
                               float* __restrict__ probs, int* __restrict__ list,
                               int* __restrict__ counts, float* __restrict__ wtok) {
    int t = blockIdx.x;
    int tid = threadIdx.x; // 64
    __shared__ float part[64][8];
    float l[8] = {0.f, 0.f, 0.f, 0.f, 0.f, 0.f, 0.f, 0.f};
    const float* hr = h2 + (size_t)t * D;
    for (int i = tid; i < D; i += 64) {
        float hv = hr[i];
        const float* g = gw + (size_t)i * E;
#pragma unroll
        for (int e = 0; e < 8; e++) l[e] += hv * g[e];
    }
#pragma unroll
    for (int e = 0; e < 8; e++) part[tid][e] = l[e];
    __syncthreads();
    if (tid == 0) {
        float lg[8];
#pragma unroll
        for (int e = 0; e < 8; e++) {
            float s = 0.f;
            for (int j = 0; j < 64; j++) s += part[j][e];
            lg[e] = s;
        }
        float m = lg[0];
#pragma unroll
        for (int e = 1; e < 8; e++) m = fmaxf(m, lg[e]);
        float se = 0.f;
        float pr[8];
#pragma unroll
        for (int e = 0; e < 8; e++) { pr[e] = expf(lg[e] - m); se += pr[e]; }
#pragma unroll
        for (int e = 0; e < 8; e++) { pr[e] /= se; probs[t * 8 + e] = pr[e]; }
        int i0 = 0;
#pragma unroll
        for (int e = 1; e < 8; e++) if (pr[e] > pr[i0]) i0 = e;
        int i1 = -1;
#pragma unroll
        for (int e = 0; e < 8; e++) {
            if (e == i0) continue;
            if (i1 < 0 || pr[e] > pr[i1]) i1 = e;
        }
        float w0 = pr[i0], w1 = pr[i1];
        float wsum = w0 + w1;
        wtok[t * 2 + 0] = w0 / wsum;
        wtok[t * 2 + 1] = w1 / wsum;
        int p0 = atomicAdd(&counts[i0], 1); list[i0 * T + p0] = t * 2 + 0;
        int p1 = atomicAdd(&counts[i1], 1); list[i1 * T + p1] = t * 2 + 1;
    }
}

// ---- MoE tile-map setup (unchanged) ----
__global__ void moe_setup_kernel(const int* __restrict__ counts,
                                 int* __restrict__ m2e_u, int* __restrict__ m2mb_u,
                                 int* __restrict__ m2e_d, int* __restrict__ m2mb_d,
                                 int* __restrict__ ntm) {
    if (threadIdx.x == 0 && blockIdx.x == 0) {
        int idx = 0;
        for (int e = 0; e < E; e++) {
            int nt = (counts[e] + 127) >> 7;
            for (int i = 0; i < nt; i++) { m2e_u[idx] = e; m2mb_u[idx] = i * 128; idx++; }
        }
        ntm[0] = idx;
        idx = 0;
        for (int e = 0; e < E; e++) {
            int nt = (counts[e] + 63) >> 6;
            for (int i = 0; i < nt; i++) { m2e_d[idx] = e; m2mb_d[idx] = i * 64; idx++; }
        }
        ntm[1] = idx;
    }
}

// ---------------- aux loss: parallel tree reduce ----------------
__global__ void aux_kernel(const float* __restrict__ probs, const int* __restrict__ counts,
                           float* __restrict__ out_aux) {
    int tid = threadIdx.x; // 256
    float part[8] = {0.f, 0.f, 0.f, 0.f, 0.f, 0.f, 0.f, 0.f};
    for (int t = tid; t < T; t += 256) {
#pragma unroll
        for (int e = 0; e < 8; e++) part[e] += probs[t * 8 + e];
    }
    __shared__ float red[256][8];
#pragma unroll
    for (int e = 0; e < 8; e++) red[tid][e] = part[e];
    __syncthreads();
    for (int o = 128; o > 0; o >>= 1) {
        if (tid < o) {
#pragma unroll
            for (int e = 0; e < 8; e++) red[tid][e] += red[tid + o][e];
        }
        __syncthreads();
    }
    if (tid == 0) {
        float aux = 0.f;
        for (int e = 0; e < 8; e++) {
            float f = (float)counts[e] / (float)T;
            float P = red[0][e] / (float)T;
            aux += f * P;
        }
        out_aux[0] = (float)E * aux;
    }
}

// ---- MoE up: BM=128 x BN=64, bf16 A, LDS dbuf + lds_barrier (R19, validated) ----
__global__ __launch_bounds__(256) void moe_up_mfma(
    const short* __restrict__ h2b, const float* __restrict__ w1, const float* __restrict__ w3,
    const int* __restrict__ list, const int* __restrict__ counts,
    const int* __restrict__ m2e, const int* __restrict__ m2mb, const int* __restrict__ ntm,
    short* __restrict__ g) {
    int mi = blockIdx.y;
    if (mi >= ntm[0]) return;
    int e = m2e[mi];
    int mb = m2mb[mi];
    int n = counts[e];
    int nb = blockIdx.x * 64;
    const float* B1g = w1 + (size_t)e * D * HID + nb;
    const float* B3g = w3 + (size_t)e * D * HID + nb;
    __shared__ short As[2][128 * 64];
    __shared__ short B1s[2][64 * 64];
    __shared__ short B3s[2][64 * 64];
    __shared__ int rowpid[128];
    __shared__ int rowtok[128];
    int tid = threadIdx.x;
    int lane = tid & 63, wave = tid >> 6;
    int wr = wave >> 1, wc = wave & 1;
    if (tid < 128) {
        int r = mb + tid;
        int pid = (r < n) ? list[e * T + r] : list[e * T];
        rowpid[tid] = pid;
        rowtok[tid] = pid >> 1;
    }
    __syncthreads();

    f32x4 acc1[4][2] = {};
    f32x4 acc3[4][2] = {};
    int ar = tid >> 1, ac = (tid & 1) * 32;
    int bn = (tid & 15) * 4, bk = (tid >> 4) * 4;
    const short* Arow = h2b + (size_t)rowtok[ar] * D + ac;

    bf16x8 a_r[4];
    float4 b1_r[4], b3_r[4];
#pragma unroll
    for (int j = 0; j < 4; j++) a_r[j] = *(const bf16x8*)(Arow + j * 8);
#pragma unroll
    for (int i = 0; i < 4; i++) {
        b1_r[i] = *(const float4*)(B1g + (size_t)(bk + i) * HID + bn);
        b3_r[i] = *(const float4*)(B3g + (size_t)(bk + i) * HID + bn);
    }
#pragma unroll
    for (int j = 0; j < 4; j++) *(bf16x8*)&As[0][swzB(ar, ac + j * 8)] = a_r[j];
    *(short4*)&B1s[0][swzB(bn + 0, bk)] = make_short4(f2bf(b1_r[0].x), f2bf(b1_r[1].x), f2bf(b1_r[2].x), f2bf(b1_r[3].x));
    *(short4*)&B1s[0][swzB(bn + 1, bk)] = make_short4(f2bf(b1_r[0].y), f2bf(b1_r[1].y), f2bf(b1_r[2].y), f2bf(b1_r[3].y));
    *(short4*)&B1s[0][swzB(bn + 2, bk)] = make_short4(f2bf(b1_r[0].z), f2bf(b1_r[1].z), f2bf(b1_r[2].z), f2bf(b1_r[3].z));
    *(short4*)&B1s[0][swzB(bn + 3, bk)] = make_short4(f2bf(b1_r[0].w), f2bf(b1_r[1].w), f2bf(b1_r[2].w), f2bf(b1_r[3].w));
    *(short4*)&B3s[0][swzB(bn + 0, bk)] = make_short4(f2bf(b3_r[0].x), f2bf(b3_r[1].x), f2bf(b3_r[2].x), f2bf(b3_r[3].x));
    *(short4*)&B3s[0][swzB(bn + 1, bk)] = make_short4(f2bf(b3_r[0].y), f2bf(b3_r[1].y), f2bf(b3_r[2].y), f2bf(b3_r[3].y));
    *(short4*)&B3s[0][swzB(bn + 2, bk)] = make_short4(f2bf(b3_r[0].z), f2bf(b3_r[1].z), f2bf(b3_r[2].z), f2bf(b3_r[3].z));
    *(short4*)&B3s[0][swzB(bn + 3, bk)] = make_short4(f2bf(b3_r[0].w), f2bf(b3_r[1].w), f2bf(b3_r[2].w), f2bf(b3_r[3].w));
    lds_barrier();
#pragma unroll
    for (int j = 0; j < 4; j++) a_r[j] = *(const bf16x8*)(Arow + 64 + j * 8);
#pragma unroll
    for (int i = 0; i < 4; i++) {
        b1_r[i] = *(const float4*)(B1g + (size_t)(64 + bk + i) * HID + bn);
        b3_r[i] = *(const float4*)(B3g + (size_t)(64 + bk + i) * HID + bn);
    }

    int cur = 0;
    for (int k0 = 0; k0 < D; k0 += 64) {
        bool more = (k0 + 64) < D;
        if (more) {
            int nx = cur ^ 1;
#pragma unroll
            for (int j = 0; j < 4; j++) *(bf16x8*)&As[nx][swzB(ar, ac + j * 8)] = a_r[j];
            *(short4*)&B1s[nx][swzB(bn + 0, bk)] = make_short4(f2bf(b1_r[0].x), f2bf(b1_r[1].x), f2bf(b1_r[2].x), f2bf(b1_r[3].x));
            *(short4*)&B1s[nx][swzB(bn + 1, bk)] = make_short4(f2bf(b1_r[0].y), f2bf(b1_r[1].y), f2bf(b1_r[2].y), f2bf(b1_r[3].y));
            *(short4*)&B1s[nx][swzB(bn + 2, bk)] = make_short4(f2bf(b1_r[0].z), f2bf(b1_r[1].z), f2bf(b1_r[2].z), f2bf(b1_r[3].z));
            *(short4*)&B1s[nx][swzB(bn + 3, bk)] = make_short4(f2bf(b1_r[0].w), f2bf(b1_r[1].w), f2bf(b1_r[2].w), f2bf(b1_r[3].w));
            *(short4*)&B3s[nx][swzB(bn + 0, bk)] = make_short4(f2bf(b3_r[0].x), f2bf(b3_r[1].x), f2bf(b3_r[2].x), f2bf(b3_r[3].x));
            *(short4*)&B3s[nx][swzB(bn + 1, bk)] = make_short4(f2bf(b3_r[0].y), f2bf(b3_r[1].y), f2bf(b3_r[2].y), f2bf(b3_r[3].y));
            *(short4*)&B3s[nx][swzB(bn + 2, bk)] = make_short4(f2bf(b3_r[0].z), f2bf(b3_r[1].z), f2bf(b3_r[2].z), f2bf(b3_r[3].z));
            *(short4*)&B3s[nx][swzB(bn + 3, bk)] = make_short4(f2bf(b3_r[0].w), f2bf(b3_r[1].w), f2bf(b3_r[2].w), f2bf(b3_r[3].w));
        }
        if (k0 + 128 < D) {
#pragma unroll
            for (int j = 0; j < 4; j++) a_r[j] = *(const bf16x8*)(Arow + k0 + 128 + j * 8);
#pragma unroll
            for (int i = 0; i < 4; i++) {
                b1_r[i] = *(const float4*)(B1g + (size_t)(k0 + 128 + bk + i) * HID + bn);
                b3_r[i] = *(const float4*)(B3g + (size_t)(k0 + 128 + bk + i) * HID + bn);
            }
        }
#pragma unroll
        for (int kk = 0; kk < 64; kk += 32) {
            int krd = kk + 8 * (lane >> 4);
            bf16x8 b1f[2], b3f[2];
#pragma unroll
            for (int ni = 0; ni < 2; ni++) {
                b1f[ni] = *(const bf16x8*)&B1s[cur][swzB(wc * 32 + ni * 16 + (lane & 15), krd)];
                b3f[ni] = *(const bf16x8*)&B3s[cur][swzB(wc * 32 + ni * 16 + (lane & 15), krd)];
            }
#pragma unroll
            for (int mi2 = 0; mi2 < 4; mi2++) {
                bf16x8 af = *(const bf16x8*)&As[cur][swzB(wr * 64 + mi2 * 16 + (lane & 15), krd)];
                acc1[mi2][0] = __builtin_amdgcn_mfma_f32_16x16x32_bf16(af, b1f[0], acc1[mi2][0], 0, 0, 0);
                acc1[mi2][1] = __builtin_amdgcn_mfma_f32_16x16x32_bf16(af, b1f[1], acc1[mi2][1], 0, 0, 0);
                acc3[mi2][0] = __builtin_amdgcn_mfma_f32_16x16x32_bf16(af, b3f[0], acc3[mi2][0], 0, 0, 0);
                acc3[mi2][1] = __builtin_amdgcn_mfma_f32_16x16x32_bf16(af, b3f[1], acc3[mi2][1], 0, 0, 0);
            }
        }
        lds_barrier();
        cur ^= 1;
    }
#pragma unroll
    for (int mi2 = 0; mi2 < 4; mi2++)
#pragma unroll
        for (int ni = 0; ni < 2; ni++)
#pragma unroll
            for (int r = 0; r < 4; r++) {
                int row = wr * 64 + mi2 * 16 + (lane >> 4) * 4 + r;
                if (mb + row < n) {
                    int pid = rowpid[row];
                    int col = nb + wc * 32 + ni * 16 + (lane & 15);
                    float v1 = acc1[mi2][ni][r], v3 = acc3[mi2][ni][r];
                    float sil = v1 / (1.f + expf(-v1));
                    g[(size_t)pid * HID + col] = f2bf(sil * v3);
                }
            }
}

// ---- MoE down: BM=64, load-after-barrier + lds_barrier (R19, validated) ----
__global__ __launch_bounds__(256) void moe_down_mfma(
    const short* __restrict__ g, const float* __restrict__ w2,
    const int* __restrict__ list, const int* __restrict__ counts,
    const int* __restrict__ m2e, const int* __restrict__ m2mb, const int* __restrict__ ntm,
    float* __restrict__ yp) {
    int mi = blockIdx.y;
    if (mi >= ntm[1]) return;
    int e = m2e[mi];
    int mb = m2mb[mi];
    int n = counts[e];
    int nb = blockIdx.x * 64;
    const float* Bg = w2 + (size_t)e * HID * D + nb;
    __shared__ short As[64 * 64];
    __shared__ short Bs[64 * 64];
    __shared__ int rowpid[64];
    int tid = threadIdx.x;
    int lane = tid & 63, wave = tid >> 6;
    int wr = wave >> 1, wc = wave & 1;
    if (tid < 64) {
        int r = mb + tid;
        rowpid[tid] = (r < n) ? list[e * T + r] : list[e * T];
    }
    __syncthreads();

    f32x4 acc[2][2] = {};
    int ar0 = tid >> 3, ak0 = (tid & 7) * 8;
    int ar1 = (tid + 256) >> 3, ak1 = ((tid + 256) & 7) * 8;
    int bn = (tid & 15) * 4, bk = (tid >> 4) * 4;
    const short* Asrc0 = g + (size_t)rowpid[ar0] * HID + ak0;
    const short* Asrc1 = g + (size_t)rowpid[ar1] * HID + ak1;

    bf16x8 a_r0 = *(const bf16x8*)(Asrc0);
    bf16x8 a_r1 = *(const bf16x8*)(Asrc1);
    float4 b_r[4];
#pragma unroll
    for (int i = 0; i < 4; i++) b_r[i] = *(const float4*)(Bg + (size_t)(bk + i) * D + bn);

    for (int k0 = 0; k0 < HID; k0 += 64) {
        *(bf16x8*)&As[swzB(ar0, ak0)] = a_r0;
        *(bf16x8*)&As[swzB(ar1, ak1)] = a_r1;
        *(short4*)&Bs[swzB(bn + 0, bk)] = make_short4(f2bf(b_r[0].x), f2bf(b_r[1].x), f2bf(b_r[2].x), f2bf(b_r[3].x));
        *(short4*)&Bs[swzB(bn + 1, bk)] = make_short4(f2bf(b_r[0].y), f2bf(b_r[1].y), f2bf(b_r[2].y), f2bf(b_r[3].y));
        *(short4*)&Bs[swzB(bn + 2, bk)] = make_short4(f2bf(b_r[0].z), f2bf(b_r[1].z), f2bf(b_r[2].z), f2bf(b_r[3].z));
        *(short4*)&Bs[swzB(bn + 3, bk)] = make_short4(f2bf(b_r[0].w), f2bf(b_r[1].w), f2bf(b_r[2].w), f2bf(b_r[3].w));
        lds_barrier();
        bool more = (k0 + 64) < HID;
        if (more) {
            a_r0 = *(const bf16x8*)(Asrc0 + k0 + 64);
            a_r1 = *(const bf16x8*)(Asrc1 + k0 + 64);
#pragma unroll
            for (int i = 0; i < 4; i++) b_r[i] = *(const float4*)(Bg + (size_t)(k0 + 64 + bk + i) * D + bn);
        }
#pragma unroll
        for (int kk = 0; kk < 64; kk += 32) {
            int krd = kk + 8 * (lane >> 4);
            bf16x8 a0 = *(const bf16x8*)&As[swzB(wr * 32 + (lane & 15), krd)];
            bf16x8 a1 = *(const bf16x8*)&As[swzB(wr * 32 + 16 + (lane & 15), krd)];
            bf16x8 b0 = *(const bf16x8*)&Bs[swzB(wc * 32 + (lane & 15), krd)];
            bf16x8 b1 = *(const bf16x8*)&Bs[swzB(wc * 32 + 16 + (lane & 15), krd)];
            acc[0][0] = __builtin_amdgcn_mfma_f32_16x16x32_bf16(a0, b0, acc[0][0], 0, 0, 0);
            acc[0][1] = __builtin_amdgcn_mfma_f32_16x16x32_bf16(a0, b1, acc[0][1], 0, 0, 0);
            acc[1][0] = __builtin_amdgcn_mfma_f32_16x16x32_bf16(a1, b0, acc[1][0], 0, 0, 0);
            acc[1][1] = __builtin_amdgcn_mfma_f32_16x16x32_bf16(a1, b1, acc[1][1], 0, 0, 0);
        }
        lds_barrier();
    }
#pragma unroll
    for (int mi2 = 0; mi2 < 2; mi2++)
#pragma unroll
        for (int ni = 0; ni < 2; ni++)
#pragma unroll
            for (int r = 0; r < 4; r++) {
                int row = wr * 32 + mi2 * 16 + (lane >> 4) * 4 + r;
                if (mb + row < n) {
                    int pid = rowpid[row];
                    int col = nb + wc * 32 + ni * 16 + (lane & 15);
                    yp[(size_t)pid * D + col] = acc[mi2][ni][r];
                }
            }
}

// ---------------- final combine (unchanged) ----------------
__global__ void combine_kernel(const float* __restrict__ yp, const float* __restrict__ wtok,
                               float* __restrict__ out) {
    int idx = blockIdx.x * 256 + threadIdx.x; // T * (D/4)
    if (idx >= T * (D / 4)) return;
    int t = idx / (D / 4);
    int d4 = idx % (D / 4);
    float4 a = ((const float4*)(out + (size_t)t * D))[d4];
    float4 y0 = ((const float4*)(yp + (size_t)(2 * t) * D))[d4];
    float4 y1 = ((const float4*)(yp + (size_t)(2 * t + 1) * D))[d4];
    float w0 = wtok[2 * t], w1 = wtok[2 * t + 1];
    a.x += w0 * y0.x + w1 * y1.x;
    a.y += w0 * y0.y + w1 * y1.y;
    a.z += w0 * y0.z + w1 * y1.z;
    a.w += w0 * y0.w + w1 * y1.w;
    ((float4*)(out + (size_t)t * D))[d4] = a;
}

extern "C" void kernel_launch(void* const* d_in, const int* in_sizes, int n_in,
                              void* d_out, int out_size, void* d_ws, size_t ws_size,
                              hipStream_t stream) {
    const float* x    = (const float*)d_in[0];
    const float* n1w  = (const float*)d_in[1];
    const float* n2w  = (const float*)d_in[2];
    const float* wq   = (const float*)d_in[3];
    const float* wdkv = (const float*)d_in[4];
    const float* wuk  = (const float*)d_in[5];
    const float* wuv  = (const float*)d_in[6];
    const float* wo   = (const float*)d_in[7];
    const float* gw   = (const float*)d_in[8];
    const float* w1   = (const float*)d_in[9];
    const float* w2   = (const float*)d_in[10];
    const float* w3   = (const float*)d_in[11];
    const int*   sp   = (const int*)d_in[12];
    float* out = (float*)d_out;

    // ws layout (floats). ~27.1 MB total.
    float* ws = (float*)d_ws;
    float* A_  = ws + 0;                 // 786432: qb, later h2b(fp32)
    float* B_  = ws + 786432;            // 786432: kb, later yp[0..]
    float* C_  = ws + 1572864;           // 786432: vb, later yp[..]
    float* Dd  = ws + 2359296;           // 786432: h, later ab
    float* cb  = ws + 3145728;           // 65536
    float* probs = ws + 3211264;         // 8192
    float* wtok  = ws + 3219456;         // 2048
    int*   list  = (int*)(ws + 3221504); // 8192 ints
    int*   counts= (int*)(ws + 3229696); // 16 ints
    int*   m2e_u = (int*)(ws + 3229712); // 32 ints
    int*   m2mb_u= (int*)(ws + 3229744); // 32 ints
    int*   m2e_d = (int*)(ws + 3229776); // 64 ints
    int*   m2mb_d= (int*)(ws + 3229840); // 64 ints
    int*   ntm   = (int*)(ws + 3229904); // 16 ints
    short* h2b   = (short*)(ws + 3229920);   // T*D bf16 = 1.5 MB
    short* gch   = (short*)(ws + 3623136);   // 2T*HID bf16 = 12.58 MB
    float* yp = B_;                      // 2T*D fp32 (B_ and C_ contiguous)

    hipMemsetAsync(counts, 0, 16 * sizeof(int), stream);

    // ---- attention ----
    rmsnorm_kernel<<<T, 256, 0, stream>>>(x, n1w, Dd, h2b);                                  // h
    gemm_qdkv<<<dim3(D / 64 + 1, T / 64), 256, 0, stream>>>(Dd, wq, wdkv, A_, cb);           // qb + c fused
    gemm_kuv<<<dim3(D / 64, T / 64), 256, 0, stream>>>(cb, wuk, wuv, B_, C_, T, D, DL);      // kb, vb
    rope_kernel<<<(T * H * 32 + 255) / 256, 256, 0, stream>>>(A_, B_, sp);
    attn_mfma<<<dim3(8, H, BATCH), 256, 0, stream>>>(A_, B_, C_, Dd);                        // ab
    gemm_bf16<true><<<dim3(D / 64, T / 64), 256, 0, stream>>>(Dd, wo, x, out, T, D, D);      // x1 in out

    // ---- MoE ----
    rmsnorm_kernel<<<T, 256, 0, stream>>>(out, n2w, A_, h2b);                                // h2 (fp32 + bf16)
    routing_kernel<<<T, 64, 0, stream>>>(A_, gw, probs, list, counts, wtok);
    moe_setup_kernel<<<1, 64, 0, stream>>>(counts, m2e_u, m2mb_u, m2e_d, m2mb_d, ntm);
    aux_kernel<<<1, 256, 0, stream>>>(probs, counts, out + (out_size - 1));
    moe_up_mfma<<<dim3(HID / 64, 32), 256, 0, stream>>>(h2b, w1, w3, list, counts, m2e_u, m2mb_u, ntm, gch);
    moe_down_mfma<<<dim3(D / 64, 40), 256, 0, stream>>>(gch, w2, list, counts, m2e_d, m2mb_d, ntm, yp);
    combine_kernel<<<(T * (D / 4) + 255) / 256, 256, 0, stream>>>(yp, wtok, out);
}